// Round 20
// baseline (433.125 us; speedup 1.0000x reference)
//
#include <hip/hip_runtime.h>

#define N_P 50000
#define N_HE 5000
#define N_E 800000
#define D_IN 128
#define D_HID 256
#define N_HEADS 4
#define HEAD_DIM 64
#define CAP_HE 320
#define CAP_P  64
#define NTILE_TOT 3125   // 50000 / 16
#define NCHUNK 782       // ceil(3125 / 4) chunks of 64 rows (k_mlp1 and k_mlp23)
#define CS2 264          // LDS stride (f16 shorts) for h1

// ---- R23 radix-bucket parameters ----
#define NBIN_HE 79       // ceil(5000 / 64)
#define HEB_SHIFT 6
#define BINCAP_HE 16384  // avg 10240, sigma~100 -> 60-sigma margin
#define NBIN_P 98        // ceil(50000 / 512)
#define PB_SHIFT 9
#define BINCAP_P 12288   // avg 8163, sigma~90
#define BATCH 2048
#define NBATCH 391       // ceil(N_E / BATCH)
#define OVF_CAP 8192

typedef __attribute__((ext_vector_type(8))) short short8;
typedef __attribute__((ext_vector_type(8))) _Float16 half8;
typedef __attribute__((ext_vector_type(4))) float f32x4;

__device__ __forceinline__ short f2bs(float x) {   // fp32 -> bf16 bits (RNE)
    union { float f; unsigned u; } v; v.f = x;
    unsigned r = (v.u + 0x7FFFu + ((v.u >> 16) & 1u)) >> 16;
    return (short)r;
}
__device__ __forceinline__ float bs2f(short s) {
    union { unsigned u; float f; } v; v.u = ((unsigned)(unsigned short)s) << 16;
    return v.f;
}
__device__ __forceinline__ short f2hs(float x) {   // fp32 -> f16 bits (RNE)
    union { _Float16 h; short s; } v; v.h = (_Float16)x; return v.s;
}

__global__ void k_zero_int(int* __restrict__ p, unsigned n) {
    unsigned i = blockIdx.x * blockDim.x + threadIdx.x;
    unsigned stride = gridDim.x * blockDim.x;
    for (; i < n; i += stride) p[i] = 0;
}

// ---------------- weight prep ----------------
__global__ void k_prep(
    const float* __restrict__ Wself, const float* __restrict__ Wclu,
    const float* __restrict__ Wf1,   const float* __restrict__ Wf2,
    short* __restrict__ WselfT_hi, short* __restrict__ WselfT_lo,
    short* __restrict__ WcluT_hi,  short* __restrict__ WcluT_lo,
    short* __restrict__ Wf1T_h,
    short* __restrict__ Wf2T_h) {
    unsigned i = blockIdx.x * 256u + threadIdx.x;   // 512*256 = 131072 exact
    if (i < 16384u) {
        unsigned j = i >> 7, d = i & 127u;
        float v = Wself[d * 128 + j];
        short h = f2bs(v);
        WselfT_hi[i] = h; WselfT_lo[i] = f2bs(v - bs2f(h));
    } else if (i < 32768u) {
        unsigned ii = i - 16384u, j = ii >> 7, d = ii & 127u;
        float v = Wclu[d * 128 + j];
        short h = f2bs(v);
        WcluT_hi[ii] = h; WcluT_lo[ii] = f2bs(v - bs2f(h));
    } else if (i < 98304u) {
        unsigned ii = i - 32768u, j = ii >> 8, d = ii & 255u;
        Wf1T_h[ii] = f2hs(Wf1[d * 256 + j]);
    } else {
        unsigned ii = i - 98304u, j = ii >> 8, d = ii & 255u;
        Wf2T_h[ii] = f2hs(Wf2[d * 128 + j]);
    }
}

// ---------------- R23 pass A: LDS-staged coarse binning ----------------
// Records pack h (13b) | p<<13 (16b) in .x, weight bits in .y.
// Each block sorts its 2048-edge batch by bin in LDS, reserves one contiguous
// global range per bin (1 atomic), and flushes coalesced full-line runs.
__global__ void k_binA(
    const int* __restrict__ edge_pid, const int* __restrict__ edge_hid,
    const float* __restrict__ edge_w,
    int key_is_h, int shift, int nbin, int bincap,
    int* __restrict__ bincnt, int2* __restrict__ bins,
    int2* __restrict__ ovf, int* __restrict__ ovf_cnt) {
    __shared__ int lcnt[128];
    __shared__ int loffs[128];
    __shared__ int gbase[128];
    __shared__ int2 stage[BATCH];     // 16 KB
    __shared__ short tbin[BATCH];     // 4 KB
    int t = threadIdx.x;
    unsigned base = (unsigned)blockIdx.x * BATCH;
    int count = (int)min((unsigned)BATCH, N_E - base);
    if (t < nbin) lcnt[t] = 0;
    __syncthreads();

    int b_[8], pos_[8]; int2 rec_[8]; bool v_[8];
    #pragma unroll
    for (int j = 0; j < 8; ++j) {
        int i = j * 256 + t;
        v_[j] = (i < count);
        if (v_[j]) {
            unsigned e = base + i;
            int h = edge_hid[e], p = edge_pid[e];
            int wbits = __float_as_int(edge_w[e]);
            int b = (key_is_h ? h : p) >> shift;
            b_[j] = b;
            rec_[j] = make_int2(h | (p << 13), wbits);
            pos_[j] = atomicAdd(&lcnt[b], 1);
        }
    }
    __syncthreads();
    if (t == 0) {
        int s = 0;
        for (int b = 0; b < nbin; ++b) { loffs[b] = s; s += lcnt[b]; }
    }
    if (t < nbin) gbase[t] = lcnt[t] ? atomicAdd(&bincnt[t], lcnt[t]) : 0;
    __syncthreads();
    #pragma unroll
    for (int j = 0; j < 8; ++j) {
        if (v_[j]) {
            int idx = loffs[b_[j]] + pos_[j];
            stage[idx] = rec_[j];
            tbin[idx] = (short)b_[j];
        }
    }
    __syncthreads();
    for (int i = t; i < count; i += 256) {
        int b = tbin[i];
        int g = gbase[b] + (i - loffs[b]);
        if (g < bincap) bins[(size_t)b * bincap + g] = stage[i];
        else { int o = atomicAdd(ovf_cnt, 1); if (o < OVF_CAP) ovf[o] = stage[i]; }
    }
}

// ---------------- R23 pass B: per-bin scatter into final buckets ----------------
// ONE block per bin: the bucket window (79->200KB / 98->256KB) stays in this
// block's XCD L2, so lines accumulate ~4 entries before write-back.
__global__ void k_binB_he(
    const int* __restrict__ bincnt, const int2* __restrict__ bins,
    int* __restrict__ cnt_he, int2* __restrict__ list_he,
    int2* __restrict__ ovf, int* __restrict__ ovf_cnt) {
    int b = blockIdx.x;
    int n = min(bincnt[b], BINCAP_HE);
    const int2* src = bins + (size_t)b * BINCAP_HE;
    for (int k = threadIdx.x; k < n; k += blockDim.x) {
        int2 rec = src[k];
        int h = rec.x & 8191;
        int p = rec.x >> 13;
        int pos = atomicAdd(&cnt_he[h], 1);
        if (pos < CAP_HE) list_he[(size_t)h * CAP_HE + pos] = make_int2(p, rec.y);
        else { int o = atomicAdd(ovf_cnt, 1); if (o < OVF_CAP) ovf[o] = rec; }
    }
}

__global__ void k_binB_p(
    const int* __restrict__ bincnt, const int2* __restrict__ bins,
    int* __restrict__ cnt_p, int2* __restrict__ list_p,
    int2* __restrict__ ovf, int* __restrict__ ovf_cnt) {
    int b = blockIdx.x;
    int n = min(bincnt[b], BINCAP_P);
    const int2* src = bins + (size_t)b * BINCAP_P;
    for (int k = threadIdx.x; k < n; k += blockDim.x) {
        int2 rec = src[k];
        int h = rec.x & 8191;
        int p = rec.x >> 13;
        int pos = atomicAdd(&cnt_p[p], 1);
        if (pos < CAP_P) list_p[(size_t)p * CAP_P + pos] = make_int2(h, rec.y);
        else { int o = atomicAdd(ovf_cnt, 1); if (o < OVF_CAP) ovf[o] = rec; }
    }
}

// ---------------- fused gather + attention; 4-way K-split gather ----------------
__global__ void k_he(
    const float* __restrict__ feat,
    const int* __restrict__ cnt_he, const int2* __restrict__ list_he,
    const int2* __restrict__ ovf_he, const int* __restrict__ ovf_he_cnt,
    const float* __restrict__ Wh1, const float* __restrict__ bh1,
    const float* __restrict__ Wh2, const float* __restrict__ bh2,
    const float* __restrict__ Wfuse,
    float* __restrict__ he_weighted) {
    __shared__ float ptl[4][D_IN];     // per-wave partial rows
    __shared__ float hef[D_IN];
    __shared__ float attnv[N_HEADS];
    __shared__ float heattn;
    int h = blockIdx.x;
    int t = threadIdx.x;
    int wv = t >> 6, lane = t & 63;

    int n = cnt_he[h]; if (n > CAP_HE) n = CAP_HE;
    const int2* lst = list_he + (size_t)h * CAP_HE;
    float2 acc = make_float2(0.f, 0.f);
    #pragma unroll 4
    for (int k = wv; k < n; k += 4) {
        int2 pr = lst[k];               // broadcast within wave
        float2 f = *(const float2*)(feat + (size_t)(unsigned)pr.x * D_IN + lane * 2);
        float w = __int_as_float(pr.y);
        acc.x += f.x * w; acc.y += f.y * w;
    }
    int oc = min(*ovf_he_cnt, OVF_CAP); // normally 0; entries are packed recs
    for (int k = wv; k < oc; k += 4) {
        int2 rec = ovf_he[k];
        if ((rec.x & 8191) == h) {
            float2 f = *(const float2*)(feat + (size_t)(unsigned)(rec.x >> 13) * D_IN + lane * 2);
            float w = __int_as_float(rec.y);
            acc.x += f.x * w; acc.y += f.y * w;
        }
    }
    ptl[wv][lane * 2] = acc.x;
    ptl[wv][lane * 2 + 1] = acc.y;
    __syncthreads();
    if (t < D_IN) hef[t] = ptl[0][t] + ptl[1][t] + ptl[2][t] + ptl[3][t];
    __syncthreads();

    int head = wv, k = lane;
    float s = bh1[head * HEAD_DIM + k];
    for (int dd = 0; dd < D_IN; ++dd)
        s += hef[dd] * Wh1[(head * D_IN + dd) * HEAD_DIM + k];
    s = fmaxf(s, 0.f);
    float val = s * Wh2[head * HEAD_DIM + k];
    for (int off = 32; off; off >>= 1) val += __shfl_down(val, off);
    if (k == 0) {
        float x = val + bh2[head];
        attnv[head] = 1.f / (1.f + expf(-x));
    }
    __syncthreads();
    if (t == 0) {
        float ha = 0.f;
        #pragma unroll
        for (int hh = 0; hh < N_HEADS; ++hh) ha += attnv[hh] * Wfuse[hh];
        heattn = ha;
    }
    __syncthreads();
    if (t < D_IN) he_weighted[h * D_IN + t] = hef[t] * heattn;
}

// ---------------- cluster gather (1 protein / 128-thread block) ----------------
__global__ void k_gather_clu(
    const float* __restrict__ he_weighted,
    const int* __restrict__ cnt_p, const int2* __restrict__ list_p,
    const int2* __restrict__ ovf_p, const int* __restrict__ ovf_p_cnt,
    float* __restrict__ cluster_feat) {
    int p = blockIdx.x;
    int n = cnt_p[p]; if (n > CAP_P) n = CAP_P;
    const int2* lst = list_p + (size_t)p * CAP_P;
    int d = threadIdx.x;
    float acc = 0.f;
    #pragma unroll 4
    for (int k = 0; k < n; ++k) {
        int2 pr = lst[k];
        acc += he_weighted[(unsigned)pr.x * D_IN + d] * __int_as_float(pr.y);
    }
    int oc = min(*ovf_p_cnt, OVF_CAP);
    for (int k = 0; k < oc; ++k) {
        int2 rec = ovf_p[k];
        if ((rec.x >> 13) == p)
            acc += he_weighted[(unsigned)(rec.x & 8191) * D_IN + d] * __int_as_float(rec.y);
    }
    cluster_feat[p * D_IN + d] = acc;
}

// ---------------- MLP stage 1: cat = [feat@Wself+b | clu@Wclu+b] ----------------
// Full bf16 hi/lo 3-MFMA math (proven, ~2^-16 rel); cat stored as ONE f16 plane.
__global__ __launch_bounds__(256, 2) void k_mlp1(
    const float* __restrict__ feat, const float* __restrict__ cluster_feat,
    const short* __restrict__ WselfT_hi, const short* __restrict__ WselfT_lo, const float* __restrict__ bself,
    const short* __restrict__ WcluT_hi,  const short* __restrict__ WcluT_lo,  const float* __restrict__ bclu,
    short* __restrict__ catF) {
    int t = threadIdx.x;
    int wv = t >> 6, lane = t & 63, col = lane & 15, q = lane >> 4;
    int m0 = blockIdx.x * 64;
    int tiles = NTILE_TOT - blockIdx.x * 4; if (tiles > 4) tiles = 4;
    const float* A = (wv < 2) ? feat : cluster_feat;
    const short* bHi = (wv < 2) ? WselfT_hi : WcluT_hi;
    const short* bLo = (wv < 2) ? WselfT_lo : WcluT_lo;
    const float* bias = (wv < 2) ? bself : bclu;
    int nb = (wv & 1) * 64;
    int cofs = (wv < 2) ? 0 : 128;

    for (int ih = 0; ih < 2; ++ih) {
        short8 Bh[2][4], Bl[2][4];
        float bv[2];
        #pragma unroll
        for (int i2 = 0; i2 < 2; ++i2) {
            int n = nb + (ih * 2 + i2) * 16 + col;
            bv[i2] = bias[n];
            #pragma unroll
            for (int ks = 0; ks < 4; ++ks) {
                int kb = ks * 32 + q * 8;
                Bh[i2][ks] = *(const short8*)&bHi[n * 128 + kb];
                Bl[i2][ks] = *(const short8*)&bLo[n * 128 + kb];
            }
        }
        for (int mt = 0; mt < tiles; ++mt) {
            int row = m0 + mt * 16 + col;
            f32x4 acc[2];
            acc[0] = (f32x4){0.f, 0.f, 0.f, 0.f};
            acc[1] = (f32x4){0.f, 0.f, 0.f, 0.f};
            #pragma unroll
            for (int ks = 0; ks < 4; ++ks) {
                int kb = ks * 32 + q * 8;
                const float* ap = A + (size_t)row * D_IN + kb;
                float4 a0 = *(const float4*)ap, a1 = *(const float4*)(ap + 4);
                float av[8] = {a0.x, a0.y, a0.z, a0.w, a1.x, a1.y, a1.z, a1.w};
                short8 ah, al;
                #pragma unroll
                for (int j = 0; j < 8; ++j) {
                    short h = f2bs(av[j]); ah[j] = h; al[j] = f2bs(av[j] - bs2f(h));
                }
                #pragma unroll
                for (int i2 = 0; i2 < 2; ++i2) {
                    acc[i2] = __builtin_amdgcn_mfma_f32_16x16x32_bf16(ah, Bh[i2][ks], acc[i2], 0, 0, 0);
                    acc[i2] = __builtin_amdgcn_mfma_f32_16x16x32_bf16(al, Bh[i2][ks], acc[i2], 0, 0, 0);
                    acc[i2] = __builtin_amdgcn_mfma_f32_16x16x32_bf16(ah, Bl[i2][ks], acc[i2], 0, 0, 0);
                }
            }
            #pragma unroll
            for (int i2 = 0; i2 < 2; ++i2) {
                int n = nb + (ih * 2 + i2) * 16 + col;
                #pragma unroll
                for (int r = 0; r < 4; ++r) {
                    float v = acc[i2][r] + bv[i2];
                    size_t o = (size_t)(m0 + mt * 16 + q * 4 + r) * 256 + cofs + n;
                    catF[o] = f2hs(v);
                }
            }
        }
    }
}

// ---------------- MLP stages 2+3 (R17: M=64, f16 single-plane gate MLP) ----------------
__global__ __launch_bounds__(256, 2) void k_mlp23(
    const short* __restrict__ catF,
    const short* __restrict__ Wf1T_h, const float* __restrict__ bf1,
    const short* __restrict__ Wf2T_h, const float* __restrict__ bf2,
    const float* __restrict__ Wf3, const float* __restrict__ bf3,
    const float* __restrict__ feat, float* __restrict__ out) {
    __shared__ __align__(16) short h1Hs[64 * CS2];   // 33.8 KB (single f16 plane)
    __shared__ float fw[64 * 2];
    float* h2F = (float*)h1Hs;       // alias: 64*132*4 = 33792 B == 64*264*2 (sync-guarded)
    int t = threadIdx.x;
    int wv = t >> 6, lane = t & 63, col = lane & 15, q = lane >> 4;
    int m0 = blockIdx.x * 64;
    int tiles = NTILE_TOT - blockIdx.x * 4; if (tiles > 4) tiles = 4;
    int rows = tiles * 16;

    // ---- stage C: h1 = relu(cat @ Wf1 + bf1), f16 ----
    for (int ih = 0; ih < 2; ++ih) {
        half8 Bh[2][8];
        float bv[2];
        #pragma unroll
        for (int ii = 0; ii < 2; ++ii) {
            int n = wv * 64 + (ih * 2 + ii) * 16 + col;
            bv[ii] = bf1[n];
            #pragma unroll
            for (int ks = 0; ks < 8; ++ks) {
                int kb = ks * 32 + q * 8;
                Bh[ii][ks] = *(const half8*)&Wf1T_h[n * 256 + kb];
            }
        }
        for (int mt = 0; mt < tiles; ++mt) {
            int row = m0 + mt * 16 + col;
            f32x4 acc[2];
            acc[0] = (f32x4){0.f, 0.f, 0.f, 0.f};
            acc[1] = (f32x4){0.f, 0.f, 0.f, 0.f};
            #pragma unroll
            for (int ks = 0; ks < 8; ++ks) {
                int kb = ks * 32 + q * 8;
                half8 ah = *(const half8*)&catF[(size_t)row * 256 + kb];
                #pragma unroll
                for (int ii = 0; ii < 2; ++ii)
                    acc[ii] = __builtin_amdgcn_mfma_f32_16x16x32_f16(ah, Bh[ii][ks], acc[ii], 0, 0, 0);
            }
            #pragma unroll
            for (int ii = 0; ii < 2; ++ii) {
                int n = wv * 64 + (ih * 2 + ii) * 16 + col;
                #pragma unroll
                for (int r = 0; r < 4; ++r) {
                    float v = fmaxf(acc[ii][r] + bv[ii], 0.f);
                    int rl = mt * 16 + q * 4 + r;
                    h1Hs[rl * CS2 + n] = f2hs(v);
                }
            }
        }
    }
    __syncthreads();

    // ---- stage D: h2 = relu(h1 @ Wf2 + bf2); results in regs ----
    f32x4 acc2[2][4];
    #pragma unroll
    for (int ii = 0; ii < 2; ++ii)
        #pragma unroll
        for (int mt = 0; mt < 4; ++mt) acc2[ii][mt] = (f32x4){0.f, 0.f, 0.f, 0.f};
    for (int ii = 0; ii < 2; ++ii) {
        half8 Bh2[8];
        int n = wv * 32 + ii * 16 + col;
        #pragma unroll
        for (int ks = 0; ks < 8; ++ks) {
            int kb = ks * 32 + q * 8;
            Bh2[ks] = *(const half8*)&Wf2T_h[n * 256 + kb];
        }
        for (int mt = 0; mt < tiles; ++mt) {
            #pragma unroll
            for (int ks = 0; ks < 8; ++ks) {
                int kb = ks * 32 + q * 8;
                half8 ah = *(const half8*)&h1Hs[(mt * 16 + col) * CS2 + kb];
                acc2[ii][mt] = __builtin_amdgcn_mfma_f32_16x16x32_f16(ah, Bh2[ks], acc2[ii][mt], 0, 0, 0);
            }
        }
    }
    __syncthreads();   // all h1 reads complete before h2F overwrites the aliased region

    #pragma unroll
    for (int ii = 0; ii < 2; ++ii) {
        int n = wv * 32 + ii * 16 + col;
        float bvv = bf2[n];
        for (int mt = 0; mt < tiles; ++mt) {
            #pragma unroll
            for (int r = 0; r < 4; ++r)
                h2F[(mt * 16 + q * 4 + r) * 132 + n] = fmaxf(acc2[ii][mt][r] + bvv, 0.f);
        }
    }
    __syncthreads();

    // ---- logits + softmax: 4 threads per protein row ----
    {
        int p = t >> 2, c = t & 3;
        if (p < rows) {
            float s0 = 0.f, s1 = 0.f;
            for (int n = c * 32; n < c * 32 + 32; ++n) {
                float h = h2F[p * 132 + n];
                s0 += h * Wf3[n * 2 + 0];
                s1 += h * Wf3[n * 2 + 1];
            }
            #pragma unroll
            for (int off = 2; off; off >>= 1) {
                s0 += __shfl_down(s0, off, 4);
                s1 += __shfl_down(s1, off, 4);
            }
            if (c == 0) {
                float l0 = s0 + bf3[0], l1 = s1 + bf3[1];
                float m = fmaxf(l0, l1);
                float e0 = expf(l0 - m), e1 = expf(l1 - m);
                float inv = 1.f / (e0 + e1);
                fw[p * 2 + 0] = e0 * inv;
                fw[p * 2 + 1] = e1 * inv;
            }
        }
    }
    __syncthreads();

    // ---- fuse + residual + relu + store (f16 cat + fp32 feat) ----
    #pragma unroll
    for (int k = 0; k < 4; ++k) {
        int idx = t + k * 256;           // 0..1023 over 64 rows x 16 j-groups
        int rl = idx >> 4;
        int j = (idx & 15) * 8;
        if (rl < rows) {
            size_t ro = (size_t)(m0 + rl);
            half8 sf = *(const half8*)&catF[ro * 256 + j];
            half8 cf = *(const half8*)&catF[ro * 256 + 128 + j];
            const float* fp = feat + ro * D_IN + j;
            float4 f0 = *(const float4*)fp, f1 = *(const float4*)(fp + 4);
            float fe[8] = {f0.x, f0.y, f0.z, f0.w, f1.x, f1.y, f1.z, f1.w};
            float w0 = fw[rl * 2 + 0], w1 = fw[rl * 2 + 1];
            float o[8];
            #pragma unroll
            for (int qq = 0; qq < 8; ++qq) {
                float self_f = (float)sf[qq];
                float clu_f  = (float)cf[qq];
                o[qq] = fmaxf(self_f * w0 + clu_f * w1 + fe[qq], 0.f);
            }
            float* ob = out + ro * D_IN + j;
            *(float4*)ob = make_float4(o[0], o[1], o[2], o[3]);
            *(float4*)(ob + 4) = make_float4(o[4], o[5], o[6], o[7]);
        }
    }
}

extern "C" void kernel_launch(void* const* d_in, const int* in_sizes, int n_in,
                              void* d_out, int out_size, void* d_ws, size_t ws_size,
                              hipStream_t stream) {
    (void)in_sizes; (void)n_in; (void)out_size; (void)ws_size;
    const float* feat   = (const float*)d_in[0];
    const float* edge_w = (const float*)d_in[1];
    const float* Wself  = (const float*)d_in[2];
    const float* bself  = (const float*)d_in[3];
    const float* Wclu   = (const float*)d_in[4];
    const float* bclu   = (const float*)d_in[5];
    const float* Wh1    = (const float*)d_in[6];
    const float* bh1    = (const float*)d_in[7];
    const float* Wh2    = (const float*)d_in[8];
    const float* bh2    = (const float*)d_in[9];
    const float* Wfuse  = (const float*)d_in[10];
    const float* Wf1    = (const float*)d_in[11];
    const float* bf1_   = (const float*)d_in[12];
    const float* Wf2    = (const float*)d_in[13];
    const float* bf2_   = (const float*)d_in[14];
    const float* Wf3    = (const float*)d_in[15];
    const float* bf3_   = (const float*)d_in[16];
    const int* edge_pid = (const int*)d_in[17];
    const int* edge_hid = (const int*)d_in[18];
    float* out = (float*)d_out;

    // ---- workspace carve-up ----
    float* he_feat      = (float*)d_ws;                         // 5000*128
    float* cluster_feat = he_feat + (size_t)N_HE * D_IN;        // 50000*128
    int2* list_he = (int2*)(cluster_feat + (size_t)N_P * D_IN); // 5000*CAP_HE
    int2* list_p  = list_he + (size_t)N_HE * CAP_HE;            // 50000*CAP_P
    int2* binHE   = list_p + (size_t)N_P * CAP_P;               // NBIN_HE*BINCAP_HE
    int2* binP    = binHE + (size_t)NBIN_HE * BINCAP_HE;        // NBIN_P*BINCAP_P
    int2* ovf_he  = binP + (size_t)NBIN_P * BINCAP_P;           // OVF_CAP
    int2* ovf_p   = ovf_he + OVF_CAP;                           // OVF_CAP
    int* cnt_he   = (int*)(ovf_p + OVF_CAP);                    // 5000
    int* cnt_p    = cnt_he + N_HE;                              // 50000
    int* ovf_he_cnt = cnt_p + N_P;                              // 1
    int* ovf_p_cnt  = ovf_he_cnt + 1;                           // 1
    int* bincntHE = ovf_p_cnt + 1;                              // NBIN_HE
    int* bincntP  = bincntHE + NBIN_HE;                         // NBIN_P
    short* WselfT_hi = (short*)(bincntP + NBIN_P);              // 128*128 each
    short* WselfT_lo = WselfT_hi + 128 * 128;
    short* WcluT_hi  = WselfT_lo + 128 * 128;
    short* WcluT_lo  = WcluT_hi + 128 * 128;
    short* Wf1T_h    = WcluT_lo + 128 * 128;                    // 256*256 (f16)
    short* Wf2T_h    = Wf1T_h + 256 * 256;                      // 128*256 (f16)
    short* catF      = Wf2T_h + 128 * 256;                      // 50000*256 (f16)

    k_prep<<<512, 256, 0, stream>>>(Wself, Wclu, Wf1, Wf2,
                                    WselfT_hi, WselfT_lo, WcluT_hi, WcluT_lo,
                                    Wf1T_h, Wf2T_h);
    k_zero_int<<<64, 256, 0, stream>>>(cnt_he,
        (unsigned)(N_HE + N_P + 2 + NBIN_HE + NBIN_P));
    k_binA<<<NBATCH, 256, 0, stream>>>(edge_pid, edge_hid, edge_w,
                                       1, HEB_SHIFT, NBIN_HE, BINCAP_HE,
                                       bincntHE, binHE, ovf_he, ovf_he_cnt);
    k_binA<<<NBATCH, 256, 0, stream>>>(edge_pid, edge_hid, edge_w,
                                       0, PB_SHIFT, NBIN_P, BINCAP_P,
                                       bincntP, binP, ovf_p, ovf_p_cnt);
    k_binB_he<<<NBIN_HE, 256, 0, stream>>>(bincntHE, binHE, cnt_he, list_he,
                                           ovf_he, ovf_he_cnt);
    k_binB_p<<<NBIN_P, 256, 0, stream>>>(bincntP, binP, cnt_p, list_p,
                                         ovf_p, ovf_p_cnt);
    k_he<<<N_HE, 256, 0, stream>>>(feat, cnt_he, list_he, ovf_he, ovf_he_cnt,
                                   Wh1, bh1, Wh2, bh2, Wfuse, he_feat);
    k_gather_clu<<<N_P, 128, 0, stream>>>(he_feat, cnt_p, list_p, ovf_p, ovf_p_cnt,
                                          cluster_feat);
    k_mlp1<<<NCHUNK, 256, 0, stream>>>(feat, cluster_feat,
                                       WselfT_hi, WselfT_lo, bself,
                                       WcluT_hi, WcluT_lo, bclu, catF);
    k_mlp23<<<NCHUNK, 256, 0, stream>>>(catF,
                                        Wf1T_h, bf1_,
                                        Wf2T_h, bf2_,
                                        Wf3, bf3_, feat, out);
}

// Round 21
// 426.450 us; speedup vs baseline: 1.0157x; 1.0157x over previous
//
#include <hip/hip_runtime.h>

#define N_P 50000
#define N_HE 5000
#define N_E 800000
#define D_IN 128
#define D_HID 256
#define N_HEADS 4
#define HEAD_DIM 64
#define CAP_HE 320
#define CAP_P  64
#define NTILE_TOT 3125   // 50000 / 16
#define NCHUNK 782       // ceil(3125 / 4) chunks of 64 rows (k_mlp1 and k_mlp23)
#define CS2 264          // LDS stride (f16 shorts) for h1

// ---- radix-bucket parameters (R23, verified) ----
#define NBIN_HE 79       // ceil(5000 / 64)
#define HEB_SHIFT 6
#define BINCAP_HE 16384
#define NBIN_P 98        // ceil(50000 / 512)
#define PB_SHIFT 9
#define BINCAP_P 12288
#define BATCH 2048
#define NBATCH 391       // ceil(N_E / BATCH)
#define OVF_CAP 8192

typedef __attribute__((ext_vector_type(8))) short short8;
typedef __attribute__((ext_vector_type(8))) _Float16 half8;
typedef __attribute__((ext_vector_type(4))) float f32x4;

__device__ __forceinline__ short f2bs(float x) {   // fp32 -> bf16 bits (RNE)
    union { float f; unsigned u; } v; v.f = x;
    unsigned r = (v.u + 0x7FFFu + ((v.u >> 16) & 1u)) >> 16;
    return (short)r;
}
__device__ __forceinline__ float bs2f(short s) {
    union { unsigned u; float f; } v; v.u = ((unsigned)(unsigned short)s) << 16;
    return v.f;
}
__device__ __forceinline__ short f2hs(float x) {   // fp32 -> f16 bits (RNE)
    union { _Float16 h; short s; } v; v.h = (_Float16)x; return v.s;
}

__global__ void k_zero_int(int* __restrict__ p, unsigned n) {
    unsigned i = blockIdx.x * blockDim.x + threadIdx.x;
    unsigned stride = gridDim.x * blockDim.x;
    for (; i < n; i += stride) p[i] = 0;
}

// ---------------- feat -> f16 copy for the gather kernel (R24) ----------------
__global__ void k_feat16(const float* __restrict__ feat, short* __restrict__ feat16) {
    unsigned i = (blockIdx.x * 256u + threadIdx.x) * 8u;   // 3125*256*8 = 6.4M exact
    float4 a0 = *(const float4*)(feat + i);
    float4 a1 = *(const float4*)(feat + i + 4);
    short8 o;
    o[0] = f2hs(a0.x); o[1] = f2hs(a0.y); o[2] = f2hs(a0.z); o[3] = f2hs(a0.w);
    o[4] = f2hs(a1.x); o[5] = f2hs(a1.y); o[6] = f2hs(a1.z); o[7] = f2hs(a1.w);
    *(short8*)(feat16 + i) = o;
}

// ---------------- weight prep ----------------
__global__ void k_prep(
    const float* __restrict__ Wself, const float* __restrict__ Wclu,
    const float* __restrict__ Wf1,   const float* __restrict__ Wf2,
    short* __restrict__ WselfT_hi, short* __restrict__ WselfT_lo,
    short* __restrict__ WcluT_hi,  short* __restrict__ WcluT_lo,
    short* __restrict__ Wf1T_h,
    short* __restrict__ Wf2T_h) {
    unsigned i = blockIdx.x * 256u + threadIdx.x;   // 512*256 = 131072 exact
    if (i < 16384u) {
        unsigned j = i >> 7, d = i & 127u;
        float v = Wself[d * 128 + j];
        short h = f2bs(v);
        WselfT_hi[i] = h; WselfT_lo[i] = f2bs(v - bs2f(h));
    } else if (i < 32768u) {
        unsigned ii = i - 16384u, j = ii >> 7, d = ii & 127u;
        float v = Wclu[d * 128 + j];
        short h = f2bs(v);
        WcluT_hi[ii] = h; WcluT_lo[ii] = f2bs(v - bs2f(h));
    } else if (i < 98304u) {
        unsigned ii = i - 32768u, j = ii >> 8, d = ii & 255u;
        Wf1T_h[ii] = f2hs(Wf1[d * 256 + j]);
    } else {
        unsigned ii = i - 98304u, j = ii >> 8, d = ii & 255u;
        Wf2T_h[ii] = f2hs(Wf2[d * 128 + j]);
    }
}

// ---------------- R23 pass A: LDS-staged coarse binning ----------------
__global__ void k_binA(
    const int* __restrict__ edge_pid, const int* __restrict__ edge_hid,
    const float* __restrict__ edge_w,
    int key_is_h, int shift, int nbin, int bincap,
    int* __restrict__ bincnt, int2* __restrict__ bins,
    int2* __restrict__ ovf, int* __restrict__ ovf_cnt) {
    __shared__ int lcnt[128];
    __shared__ int loffs[128];
    __shared__ int gbase[128];
    __shared__ int2 stage[BATCH];     // 16 KB
    __shared__ short tbin[BATCH];     // 4 KB
    int t = threadIdx.x;
    unsigned base = (unsigned)blockIdx.x * BATCH;
    int count = (int)min((unsigned)BATCH, N_E - base);
    if (t < nbin) lcnt[t] = 0;
    __syncthreads();

    int b_[8], pos_[8]; int2 rec_[8]; bool v_[8];
    #pragma unroll
    for (int j = 0; j < 8; ++j) {
        int i = j * 256 + t;
        v_[j] = (i < count);
        if (v_[j]) {
            unsigned e = base + i;
            int h = edge_hid[e], p = edge_pid[e];
            int wbits = __float_as_int(edge_w[e]);
            int b = (key_is_h ? h : p) >> shift;
            b_[j] = b;
            rec_[j] = make_int2(h | (p << 13), wbits);
            pos_[j] = atomicAdd(&lcnt[b], 1);
        }
    }
    __syncthreads();
    if (t == 0) {
        int s = 0;
        for (int b = 0; b < nbin; ++b) { loffs[b] = s; s += lcnt[b]; }
    }
    if (t < nbin) gbase[t] = lcnt[t] ? atomicAdd(&bincnt[t], lcnt[t]) : 0;
    __syncthreads();
    #pragma unroll
    for (int j = 0; j < 8; ++j) {
        if (v_[j]) {
            int idx = loffs[b_[j]] + pos_[j];
            stage[idx] = rec_[j];
            tbin[idx] = (short)b_[j];
        }
    }
    __syncthreads();
    for (int i = t; i < count; i += 256) {
        int b = tbin[i];
        int g = gbase[b] + (i - loffs[b]);
        if (g < bincap) bins[(size_t)b * bincap + g] = stage[i];
        else { int o = atomicAdd(ovf_cnt, 1); if (o < OVF_CAP) ovf[o] = stage[i]; }
    }
}

// ---------------- R23 pass B: per-bin scatter into final buckets ----------------
__global__ void k_binB_he(
    const int* __restrict__ bincnt, const int2* __restrict__ bins,
    int* __restrict__ cnt_he, int2* __restrict__ list_he,
    int2* __restrict__ ovf, int* __restrict__ ovf_cnt) {
    int b = blockIdx.x;
    int n = min(bincnt[b], BINCAP_HE);
    const int2* src = bins + (size_t)b * BINCAP_HE;
    for (int k = threadIdx.x; k < n; k += blockDim.x) {
        int2 rec = src[k];
        int h = rec.x & 8191;
        int p = rec.x >> 13;
        int pos = atomicAdd(&cnt_he[h], 1);
        if (pos < CAP_HE) list_he[(size_t)h * CAP_HE + pos] = make_int2(p, rec.y);
        else { int o = atomicAdd(ovf_cnt, 1); if (o < OVF_CAP) ovf[o] = rec; }
    }
}

__global__ void k_binB_p(
    const int* __restrict__ bincnt, const int2* __restrict__ bins,
    int* __restrict__ cnt_p, int2* __restrict__ list_p,
    int2* __restrict__ ovf, int* __restrict__ ovf_cnt) {
    int b = blockIdx.x;
    int n = min(bincnt[b], BINCAP_P);
    const int2* src = bins + (size_t)b * BINCAP_P;
    for (int k = threadIdx.x; k < n; k += blockDim.x) {
        int2 rec = src[k];
        int h = rec.x & 8191;
        int p = rec.x >> 13;
        int pos = atomicAdd(&cnt_p[p], 1);
        if (pos < CAP_P) list_p[(size_t)p * CAP_P + pos] = make_int2(h, rec.y);
        else { int o = atomicAdd(ovf_cnt, 1); if (o < OVF_CAP) ovf[o] = rec; }
    }
}

// ---------------- fused gather + attention (R24: f16 feat gather, halves traffic) ----------------
__global__ void k_he(
    const short* __restrict__ feat16,
    const int* __restrict__ cnt_he, const int2* __restrict__ list_he,
    const int2* __restrict__ ovf_he, const int* __restrict__ ovf_he_cnt,
    const float* __restrict__ Wh1, const float* __restrict__ bh1,
    const float* __restrict__ Wh2, const float* __restrict__ bh2,
    const float* __restrict__ Wfuse,
    float* __restrict__ he_weighted) {
    __shared__ float ptl[4][D_IN];     // per-wave partial rows
    __shared__ float hef[D_IN];
    __shared__ float attnv[N_HEADS];
    __shared__ float heattn;
    int h = blockIdx.x;
    int t = threadIdx.x;
    int wv = t >> 6, lane = t & 63;

    int n = cnt_he[h]; if (n > CAP_HE) n = CAP_HE;
    const int2* lst = list_he + (size_t)h * CAP_HE;
    float2 acc = make_float2(0.f, 0.f);
    #pragma unroll 4
    for (int k = wv; k < n; k += 4) {
        int2 pr = lst[k];               // broadcast within wave
        union { unsigned u; _Float16 hh[2]; } cv;
        cv.u = *(const unsigned*)(feat16 + (size_t)(unsigned)pr.x * D_IN + lane * 2);
        float w = __int_as_float(pr.y);
        acc.x += (float)cv.hh[0] * w; acc.y += (float)cv.hh[1] * w;
    }
    int oc = min(*ovf_he_cnt, OVF_CAP); // normally 0; entries are packed recs
    for (int k = wv; k < oc; k += 4) {
        int2 rec = ovf_he[k];
        if ((rec.x & 8191) == h) {
            union { unsigned u; _Float16 hh[2]; } cv;
            cv.u = *(const unsigned*)(feat16 + (size_t)(unsigned)(rec.x >> 13) * D_IN + lane * 2);
            float w = __int_as_float(rec.y);
            acc.x += (float)cv.hh[0] * w; acc.y += (float)cv.hh[1] * w;
        }
    }
    ptl[wv][lane * 2] = acc.x;
    ptl[wv][lane * 2 + 1] = acc.y;
    __syncthreads();
    if (t < D_IN) hef[t] = ptl[0][t] + ptl[1][t] + ptl[2][t] + ptl[3][t];
    __syncthreads();

    int head = wv, k = lane;
    float s = bh1[head * HEAD_DIM + k];
    for (int dd = 0; dd < D_IN; ++dd)
        s += hef[dd] * Wh1[(head * D_IN + dd) * HEAD_DIM + k];
    s = fmaxf(s, 0.f);
    float val = s * Wh2[head * HEAD_DIM + k];
    for (int off = 32; off; off >>= 1) val += __shfl_down(val, off);
    if (k == 0) {
        float x = val + bh2[head];
        attnv[head] = 1.f / (1.f + expf(-x));
    }
    __syncthreads();
    if (t == 0) {
        float ha = 0.f;
        #pragma unroll
        for (int hh = 0; hh < N_HEADS; ++hh) ha += attnv[hh] * Wfuse[hh];
        heattn = ha;
    }
    __syncthreads();
    if (t < D_IN) he_weighted[h * D_IN + t] = hef[t] * heattn;
}

// ---------------- cluster gather (1 protein / 128-thread block) ----------------
__global__ void k_gather_clu(
    const float* __restrict__ he_weighted,
    const int* __restrict__ cnt_p, const int2* __restrict__ list_p,
    const int2* __restrict__ ovf_p, const int* __restrict__ ovf_p_cnt,
    float* __restrict__ cluster_feat) {
    int p = blockIdx.x;
    int n = cnt_p[p]; if (n > CAP_P) n = CAP_P;
    const int2* lst = list_p + (size_t)p * CAP_P;
    int d = threadIdx.x;
    float acc = 0.f;
    #pragma unroll 4
    for (int k = 0; k < n; ++k) {
        int2 pr = lst[k];
        acc += he_weighted[(unsigned)pr.x * D_IN + d] * __int_as_float(pr.y);
    }
    int oc = min(*ovf_p_cnt, OVF_CAP);
    for (int k = 0; k < oc; ++k) {
        int2 rec = ovf_p[k];
        if ((rec.x >> 13) == p)
            acc += he_weighted[(unsigned)(rec.x & 8191) * D_IN + d] * __int_as_float(rec.y);
    }
    cluster_feat[p * D_IN + d] = acc;
}

// ---------------- MLP stage 1: cat = [feat@Wself+b | clu@Wclu+b] ----------------
// Full bf16 hi/lo 3-MFMA math (proven, ~2^-16 rel); cat stored as ONE f16 plane.
__global__ __launch_bounds__(256, 2) void k_mlp1(
    const float* __restrict__ feat, const float* __restrict__ cluster_feat,
    const short* __restrict__ WselfT_hi, const short* __restrict__ WselfT_lo, const float* __restrict__ bself,
    const short* __restrict__ WcluT_hi,  const short* __restrict__ WcluT_lo,  const float* __restrict__ bclu,
    short* __restrict__ catF) {
    int t = threadIdx.x;
    int wv = t >> 6, lane = t & 63, col = lane & 15, q = lane >> 4;
    int m0 = blockIdx.x * 64;
    int tiles = NTILE_TOT - blockIdx.x * 4; if (tiles > 4) tiles = 4;
    const float* A = (wv < 2) ? feat : cluster_feat;
    const short* bHi = (wv < 2) ? WselfT_hi : WcluT_hi;
    const short* bLo = (wv < 2) ? WselfT_lo : WcluT_lo;
    const float* bias = (wv < 2) ? bself : bclu;
    int nb = (wv & 1) * 64;
    int cofs = (wv < 2) ? 0 : 128;

    for (int ih = 0; ih < 2; ++ih) {
        short8 Bh[2][4], Bl[2][4];
        float bv[2];
        #pragma unroll
        for (int i2 = 0; i2 < 2; ++i2) {
            int n = nb + (ih * 2 + i2) * 16 + col;
            bv[i2] = bias[n];
            #pragma unroll
            for (int ks = 0; ks < 4; ++ks) {
                int kb = ks * 32 + q * 8;
                Bh[i2][ks] = *(const short8*)&bHi[n * 128 + kb];
                Bl[i2][ks] = *(const short8*)&bLo[n * 128 + kb];
            }
        }
        for (int mt = 0; mt < tiles; ++mt) {
            int row = m0 + mt * 16 + col;
            f32x4 acc[2];
            acc[0] = (f32x4){0.f, 0.f, 0.f, 0.f};
            acc[1] = (f32x4){0.f, 0.f, 0.f, 0.f};
            #pragma unroll
            for (int ks = 0; ks < 4; ++ks) {
                int kb = ks * 32 + q * 8;
                const float* ap = A + (size_t)row * D_IN + kb;
                float4 a0 = *(const float4*)ap, a1 = *(const float4*)(ap + 4);
                float av[8] = {a0.x, a0.y, a0.z, a0.w, a1.x, a1.y, a1.z, a1.w};
                short8 ah, al;
                #pragma unroll
                for (int j = 0; j < 8; ++j) {
                    short h = f2bs(av[j]); ah[j] = h; al[j] = f2bs(av[j] - bs2f(h));
                }
                #pragma unroll
                for (int i2 = 0; i2 < 2; ++i2) {
                    acc[i2] = __builtin_amdgcn_mfma_f32_16x16x32_bf16(ah, Bh[i2][ks], acc[i2], 0, 0, 0);
                    acc[i2] = __builtin_amdgcn_mfma_f32_16x16x32_bf16(al, Bh[i2][ks], acc[i2], 0, 0, 0);
                    acc[i2] = __builtin_amdgcn_mfma_f32_16x16x32_bf16(ah, Bl[i2][ks], acc[i2], 0, 0, 0);
                }
            }
            #pragma unroll
            for (int i2 = 0; i2 < 2; ++i2) {
                int n = nb + (ih * 2 + i2) * 16 + col;
                #pragma unroll
                for (int r = 0; r < 4; ++r) {
                    float v = acc[i2][r] + bv[i2];
                    size_t o = (size_t)(m0 + mt * 16 + q * 4 + r) * 256 + cofs + n;
                    catF[o] = f2hs(v);
                }
            }
        }
    }
}

// ---------------- MLP stages 2+3 (R17: M=64, f16 single-plane gate MLP) ----------------
__global__ __launch_bounds__(256, 2) void k_mlp23(
    const short* __restrict__ catF,
    const short* __restrict__ Wf1T_h, const float* __restrict__ bf1,
    const short* __restrict__ Wf2T_h, const float* __restrict__ bf2,
    const float* __restrict__ Wf3, const float* __restrict__ bf3,
    const float* __restrict__ feat, float* __restrict__ out) {
    __shared__ __align__(16) short h1Hs[64 * CS2];   // 33.8 KB (single f16 plane)
    __shared__ float fw[64 * 2];
    float* h2F = (float*)h1Hs;       // alias: 64*132*4 = 33792 B == 64*264*2 (sync-guarded)
    int t = threadIdx.x;
    int wv = t >> 6, lane = t & 63, col = lane & 15, q = lane >> 4;
    int m0 = blockIdx.x * 64;
    int tiles = NTILE_TOT - blockIdx.x * 4; if (tiles > 4) tiles = 4;
    int rows = tiles * 16;

    // ---- stage C: h1 = relu(cat @ Wf1 + bf1), f16 ----
    for (int ih = 0; ih < 2; ++ih) {
        half8 Bh[2][8];
        float bv[2];
        #pragma unroll
        for (int ii = 0; ii < 2; ++ii) {
            int n = wv * 64 + (ih * 2 + ii) * 16 + col;
            bv[ii] = bf1[n];
            #pragma unroll
            for (int ks = 0; ks < 8; ++ks) {
                int kb = ks * 32 + q * 8;
                Bh[ii][ks] = *(const half8*)&Wf1T_h[n * 256 + kb];
            }
        }
        for (int mt = 0; mt < tiles; ++mt) {
            int row = m0 + mt * 16 + col;
            f32x4 acc[2];
            acc[0] = (f32x4){0.f, 0.f, 0.f, 0.f};
            acc[1] = (f32x4){0.f, 0.f, 0.f, 0.f};
            #pragma unroll
            for (int ks = 0; ks < 8; ++ks) {
                int kb = ks * 32 + q * 8;
                half8 ah = *(const half8*)&catF[(size_t)row * 256 + kb];
                #pragma unroll
                for (int ii = 0; ii < 2; ++ii)
                    acc[ii] = __builtin_amdgcn_mfma_f32_16x16x32_f16(ah, Bh[ii][ks], acc[ii], 0, 0, 0);
            }
            #pragma unroll
            for (int ii = 0; ii < 2; ++ii) {
                int n = wv * 64 + (ih * 2 + ii) * 16 + col;
                #pragma unroll
                for (int r = 0; r < 4; ++r) {
                    float v = fmaxf(acc[ii][r] + bv[ii], 0.f);
                    int rl = mt * 16 + q * 4 + r;
                    h1Hs[rl * CS2 + n] = f2hs(v);
                }
            }
        }
    }
    __syncthreads();

    // ---- stage D: h2 = relu(h1 @ Wf2 + bf2); results in regs ----
    f32x4 acc2[2][4];
    #pragma unroll
    for (int ii = 0; ii < 2; ++ii)
        #pragma unroll
        for (int mt = 0; mt < 4; ++mt) acc2[ii][mt] = (f32x4){0.f, 0.f, 0.f, 0.f};
    for (int ii = 0; ii < 2; ++ii) {
        half8 Bh2[8];
        int n = wv * 32 + ii * 16 + col;
        #pragma unroll
        for (int ks = 0; ks < 8; ++ks) {
            int kb = ks * 32 + q * 8;
            Bh2[ks] = *(const half8*)&Wf2T_h[n * 256 + kb];
        }
        for (int mt = 0; mt < tiles; ++mt) {
            #pragma unroll
            for (int ks = 0; ks < 8; ++ks) {
                int kb = ks * 32 + q * 8;
                half8 ah = *(const half8*)&h1Hs[(mt * 16 + col) * CS2 + kb];
                acc2[ii][mt] = __builtin_amdgcn_mfma_f32_16x16x32_f16(ah, Bh2[ks], acc2[ii][mt], 0, 0, 0);
            }
        }
    }
    __syncthreads();   // all h1 reads complete before h2F overwrites the aliased region

    #pragma unroll
    for (int ii = 0; ii < 2; ++ii) {
        int n = wv * 32 + ii * 16 + col;
        float bvv = bf2[n];
        for (int mt = 0; mt < tiles; ++mt) {
            #pragma unroll
            for (int r = 0; r < 4; ++r)
                h2F[(mt * 16 + q * 4 + r) * 132 + n] = fmaxf(acc2[ii][mt][r] + bvv, 0.f);
        }
    }
    __syncthreads();

    // ---- logits + softmax: 4 threads per protein row ----
    {
        int p = t >> 2, c = t & 3;
        if (p < rows) {
            float s0 = 0.f, s1 = 0.f;
            for (int n = c * 32; n < c * 32 + 32; ++n) {
                float h = h2F[p * 132 + n];
                s0 += h * Wf3[n * 2 + 0];
                s1 += h * Wf3[n * 2 + 1];
            }
            #pragma unroll
            for (int off = 2; off; off >>= 1) {
                s0 += __shfl_down(s0, off, 4);
                s1 += __shfl_down(s1, off, 4);
            }
            if (c == 0) {
                float l0 = s0 + bf3[0], l1 = s1 + bf3[1];
                float m = fmaxf(l0, l1);
                float e0 = expf(l0 - m), e1 = expf(l1 - m);
                float inv = 1.f / (e0 + e1);
                fw[p * 2 + 0] = e0 * inv;
                fw[p * 2 + 1] = e1 * inv;
            }
        }
    }
    __syncthreads();

    // ---- fuse + residual + relu + store (f16 cat + fp32 feat) ----
    #pragma unroll
    for (int k = 0; k < 4; ++k) {
        int idx = t + k * 256;           // 0..1023 over 64 rows x 16 j-groups
        int rl = idx >> 4;
        int j = (idx & 15) * 8;
        if (rl < rows) {
            size_t ro = (size_t)(m0 + rl);
            half8 sf = *(const half8*)&catF[ro * 256 + j];
            half8 cf = *(const half8*)&catF[ro * 256 + 128 + j];
            const float* fp = feat + ro * D_IN + j;
            float4 f0 = *(const float4*)fp, f1 = *(const float4*)(fp + 4);
            float fe[8] = {f0.x, f0.y, f0.z, f0.w, f1.x, f1.y, f1.z, f1.w};
            float w0 = fw[rl * 2 + 0], w1 = fw[rl * 2 + 1];
            float o[8];
            #pragma unroll
            for (int qq = 0; qq < 8; ++qq) {
                float self_f = (float)sf[qq];
                float clu_f  = (float)cf[qq];
                o[qq] = fmaxf(self_f * w0 + clu_f * w1 + fe[qq], 0.f);
            }
            float* ob = out + ro * D_IN + j;
            *(float4*)ob = make_float4(o[0], o[1], o[2], o[3]);
            *(float4*)(ob + 4) = make_float4(o[4], o[5], o[6], o[7]);
        }
    }
}

extern "C" void kernel_launch(void* const* d_in, const int* in_sizes, int n_in,
                              void* d_out, int out_size, void* d_ws, size_t ws_size,
                              hipStream_t stream) {
    (void)in_sizes; (void)n_in; (void)out_size; (void)ws_size;
    const float* feat   = (const float*)d_in[0];
    const float* edge_w = (const float*)d_in[1];
    const float* Wself  = (const float*)d_in[2];
    const float* bself  = (const float*)d_in[3];
    const float* Wclu   = (const float*)d_in[4];
    const float* bclu   = (const float*)d_in[5];
    const float* Wh1    = (const float*)d_in[6];
    const float* bh1    = (const float*)d_in[7];
    const float* Wh2    = (const float*)d_in[8];
    const float* bh2    = (const float*)d_in[9];
    const float* Wfuse  = (const float*)d_in[10];
    const float* Wf1    = (const float*)d_in[11];
    const float* bf1_   = (const float*)d_in[12];
    const float* Wf2    = (const float*)d_in[13];
    const float* bf2_   = (const float*)d_in[14];
    const float* Wf3    = (const float*)d_in[15];
    const float* bf3_   = (const float*)d_in[16];
    const int* edge_pid = (const int*)d_in[17];
    const int* edge_hid = (const int*)d_in[18];
    float* out = (float*)d_out;

    // ---- workspace carve-up ----
    float* he_feat      = (float*)d_ws;                         // 5000*128
    float* cluster_feat = he_feat + (size_t)N_HE * D_IN;        // 50000*128
    int2* list_he = (int2*)(cluster_feat + (size_t)N_P * D_IN); // 5000*CAP_HE
    int2* list_p  = list_he + (size_t)N_HE * CAP_HE;            // 50000*CAP_P
    int2* binHE   = list_p + (size_t)N_P * CAP_P;               // NBIN_HE*BINCAP_HE
    int2* binP    = binHE + (size_t)NBIN_HE * BINCAP_HE;        // NBIN_P*BINCAP_P
    int2* ovf_he  = binP + (size_t)NBIN_P * BINCAP_P;           // OVF_CAP
    int2* ovf_p   = ovf_he + OVF_CAP;                           // OVF_CAP
    int* cnt_he   = (int*)(ovf_p + OVF_CAP);                    // 5000
    int* cnt_p    = cnt_he + N_HE;                              // 50000
    int* ovf_he_cnt = cnt_p + N_P;                              // 1
    int* ovf_p_cnt  = ovf_he_cnt + 1;                           // 1
    int* bincntHE = ovf_p_cnt + 1;                              // NBIN_HE
    int* bincntP  = bincntHE + NBIN_HE;                         // NBIN_P
    short* WselfT_hi = (short*)(bincntP + NBIN_P);              // 128*128 each
    short* WselfT_lo = WselfT_hi + 128 * 128;
    short* WcluT_hi  = WselfT_lo + 128 * 128;
    short* WcluT_lo  = WcluT_hi + 128 * 128;
    short* Wf1T_h    = WcluT_lo + 128 * 128;                    // 256*256 (f16)
    short* Wf2T_h    = Wf1T_h + 256 * 256;                      // 128*256 (f16)
    short* catF      = Wf2T_h + 128 * 256;                      // 50000*256 (f16)
    short* feat16    = catF + (size_t)N_P * 256;                // 50000*128 (f16)

    k_prep<<<512, 256, 0, stream>>>(Wself, Wclu, Wf1, Wf2,
                                    WselfT_hi, WselfT_lo, WcluT_hi, WcluT_lo,
                                    Wf1T_h, Wf2T_h);
    k_feat16<<<3125, 256, 0, stream>>>(feat, feat16);
    k_zero_int<<<64, 256, 0, stream>>>(cnt_he,
        (unsigned)(N_HE + N_P + 2 + NBIN_HE + NBIN_P));
    k_binA<<<NBATCH, 256, 0, stream>>>(edge_pid, edge_hid, edge_w,
                                       1, HEB_SHIFT, NBIN_HE, BINCAP_HE,
                                       bincntHE, binHE, ovf_he, ovf_he_cnt);
    k_binA<<<NBATCH, 256, 0, stream>>>(edge_pid, edge_hid, edge_w,
                                       0, PB_SHIFT, NBIN_P, BINCAP_P,
                                       bincntP, binP, ovf_p, ovf_p_cnt);
    k_binB_he<<<NBIN_HE, 256, 0, stream>>>(bincntHE, binHE, cnt_he, list_he,
                                           ovf_he, ovf_he_cnt);
    k_binB_p<<<NBIN_P, 256, 0, stream>>>(bincntP, binP, cnt_p, list_p,
                                         ovf_p, ovf_p_cnt);
    k_he<<<N_HE, 256, 0, stream>>>(feat16, cnt_he, list_he, ovf_he, ovf_he_cnt,
                                   Wh1, bh1, Wh2, bh2, Wfuse, he_feat);
    k_gather_clu<<<N_P, 128, 0, stream>>>(he_feat, cnt_p, list_p, ovf_p, ovf_p_cnt,
                                          cluster_feat);
    k_mlp1<<<NCHUNK, 256, 0, stream>>>(feat, cluster_feat,
                                       WselfT_hi, WselfT_lo, bself,
                                       WcluT_hi, WcluT_lo, bclu, catF);
    k_mlp23<<<NCHUNK, 256, 0, stream>>>(catF,
                                        Wf1T_h, bf1_,
                                        Wf2T_h, bf2_,
                                        Wf3, bf3_, feat, out);
}

// Round 22
// 391.708 us; speedup vs baseline: 1.1057x; 1.0887x over previous
//
#include <hip/hip_runtime.h>

#define N_P 50000
#define N_HE 5000
#define N_E 800000
#define D_IN 128
#define D_HID 256
#define N_HEADS 4
#define HEAD_DIM 64
#define CAP_HE 320
#define CAP_P  64
#define NTILE_TOT 3125   // 50000 / 16
#define NCHUNK 782       // ceil(3125 / 4) chunks of 64 rows
#define CS2 264          // LDS stride (f16 shorts) for cat/h1

// ---- radix-bucket parameters (R23, verified) ----
#define NBIN_HE 79       // ceil(5000 / 64)
#define HEB_SHIFT 6
#define BINCAP_HE 16384
#define NBIN_P 98        // ceil(50000 / 512)
#define PB_SHIFT 9
#define BINCAP_P 12288
#define BATCH 2048
#define NBATCH 391       // ceil(N_E / BATCH)
#define OVF_CAP 8192

typedef __attribute__((ext_vector_type(8))) short short8;
typedef __attribute__((ext_vector_type(8))) _Float16 half8;
typedef __attribute__((ext_vector_type(4))) float f32x4;

__device__ __forceinline__ short f2bs(float x) {   // fp32 -> bf16 bits (RNE)
    union { float f; unsigned u; } v; v.f = x;
    unsigned r = (v.u + 0x7FFFu + ((v.u >> 16) & 1u)) >> 16;
    return (short)r;
}
__device__ __forceinline__ float bs2f(short s) {
    union { unsigned u; float f; } v; v.u = ((unsigned)(unsigned short)s) << 16;
    return v.f;
}
__device__ __forceinline__ short f2hs(float x) {   // fp32 -> f16 bits (RNE)
    union { _Float16 h; short s; } v; v.h = (_Float16)x; return v.s;
}

__global__ void k_zero_int(int* __restrict__ p, unsigned n) {
    unsigned i = blockIdx.x * blockDim.x + threadIdx.x;
    unsigned stride = gridDim.x * blockDim.x;
    for (; i < n; i += stride) p[i] = 0;
}

// ---------------- feat -> f16 copy for the gather kernel (R24, verified) ----------------
__global__ void k_feat16(const float* __restrict__ feat, short* __restrict__ feat16) {
    unsigned i = (blockIdx.x * 256u + threadIdx.x) * 8u;   // 3125*256*8 = 6.4M exact
    float4 a0 = *(const float4*)(feat + i);
    float4 a1 = *(const float4*)(feat + i + 4);
    short8 o;
    o[0] = f2hs(a0.x); o[1] = f2hs(a0.y); o[2] = f2hs(a0.z); o[3] = f2hs(a0.w);
    o[4] = f2hs(a1.x); o[5] = f2hs(a1.y); o[6] = f2hs(a1.z); o[7] = f2hs(a1.w);
    *(short8*)(feat16 + i) = o;
}

// ---------------- weight prep ----------------
__global__ void k_prep(
    const float* __restrict__ Wself, const float* __restrict__ Wclu,
    const float* __restrict__ Wf1,   const float* __restrict__ Wf2,
    short* __restrict__ WselfT_hi, short* __restrict__ WselfT_lo,
    short* __restrict__ WcluT_hi,  short* __restrict__ WcluT_lo,
    short* __restrict__ Wf1T_h,
    short* __restrict__ Wf2T_h) {
    unsigned i = blockIdx.x * 256u + threadIdx.x;   // 512*256 = 131072 exact
    if (i < 16384u) {
        unsigned j = i >> 7, d = i & 127u;
        float v = Wself[d * 128 + j];
        short h = f2bs(v);
        WselfT_hi[i] = h; WselfT_lo[i] = f2bs(v - bs2f(h));
    } else if (i < 32768u) {
        unsigned ii = i - 16384u, j = ii >> 7, d = ii & 127u;
        float v = Wclu[d * 128 + j];
        short h = f2bs(v);
        WcluT_hi[ii] = h; WcluT_lo[ii] = f2bs(v - bs2f(h));
    } else if (i < 98304u) {
        unsigned ii = i - 32768u, j = ii >> 8, d = ii & 255u;
        Wf1T_h[ii] = f2hs(Wf1[d * 256 + j]);
    } else {
        unsigned ii = i - 98304u, j = ii >> 8, d = ii & 255u;
        Wf2T_h[ii] = f2hs(Wf2[d * 128 + j]);
    }
}

// ---------------- R23 pass A: LDS-staged coarse binning ----------------
__global__ void k_binA(
    const int* __restrict__ edge_pid, const int* __restrict__ edge_hid,
    const float* __restrict__ edge_w,
    int key_is_h, int shift, int nbin, int bincap,
    int* __restrict__ bincnt, int2* __restrict__ bins,
    int2* __restrict__ ovf, int* __restrict__ ovf_cnt) {
    __shared__ int lcnt[128];
    __shared__ int loffs[128];
    __shared__ int gbase[128];
    __shared__ int2 stage[BATCH];     // 16 KB
    __shared__ short tbin[BATCH];     // 4 KB
    int t = threadIdx.x;
    unsigned base = (unsigned)blockIdx.x * BATCH;
    int count = (int)min((unsigned)BATCH, N_E - base);
    if (t < nbin) lcnt[t] = 0;
    __syncthreads();

    int b_[8], pos_[8]; int2 rec_[8]; bool v_[8];
    #pragma unroll
    for (int j = 0; j < 8; ++j) {
        int i = j * 256 + t;
        v_[j] = (i < count);
        if (v_[j]) {
            unsigned e = base + i;
            int h = edge_hid[e], p = edge_pid[e];
            int wbits = __float_as_int(edge_w[e]);
            int b = (key_is_h ? h : p) >> shift;
            b_[j] = b;
            rec_[j] = make_int2(h | (p << 13), wbits);
            pos_[j] = atomicAdd(&lcnt[b], 1);
        }
    }
    __syncthreads();
    if (t == 0) {
        int s = 0;
        for (int b = 0; b < nbin; ++b) { loffs[b] = s; s += lcnt[b]; }
    }
    if (t < nbin) gbase[t] = lcnt[t] ? atomicAdd(&bincnt[t], lcnt[t]) : 0;
    __syncthreads();
    #pragma unroll
    for (int j = 0; j < 8; ++j) {
        if (v_[j]) {
            int idx = loffs[b_[j]] + pos_[j];
            stage[idx] = rec_[j];
            tbin[idx] = (short)b_[j];
        }
    }
    __syncthreads();
    for (int i = t; i < count; i += 256) {
        int b = tbin[i];
        int g = gbase[b] + (i - loffs[b]);
        if (g < bincap) bins[(size_t)b * bincap + g] = stage[i];
        else { int o = atomicAdd(ovf_cnt, 1); if (o < OVF_CAP) ovf[o] = stage[i]; }
    }
}

// ---------------- R23 pass B: per-bin scatter into final buckets ----------------
__global__ void k_binB_he(
    const int* __restrict__ bincnt, const int2* __restrict__ bins,
    int* __restrict__ cnt_he, int2* __restrict__ list_he,
    int2* __restrict__ ovf, int* __restrict__ ovf_cnt) {
    int b = blockIdx.x;
    int n = min(bincnt[b], BINCAP_HE);
    const int2* src = bins + (size_t)b * BINCAP_HE;
    for (int k = threadIdx.x; k < n; k += blockDim.x) {
        int2 rec = src[k];
        int h = rec.x & 8191;
        int p = rec.x >> 13;
        int pos = atomicAdd(&cnt_he[h], 1);
        if (pos < CAP_HE) list_he[(size_t)h * CAP_HE + pos] = make_int2(p, rec.y);
        else { int o = atomicAdd(ovf_cnt, 1); if (o < OVF_CAP) ovf[o] = rec; }
    }
}

__global__ void k_binB_p(
    const int* __restrict__ bincnt, const int2* __restrict__ bins,
    int* __restrict__ cnt_p, int2* __restrict__ list_p,
    int2* __restrict__ ovf, int* __restrict__ ovf_cnt) {
    int b = blockIdx.x;
    int n = min(bincnt[b], BINCAP_P);
    const int2* src = bins + (size_t)b * BINCAP_P;
    for (int k = threadIdx.x; k < n; k += blockDim.x) {
        int2 rec = src[k];
        int h = rec.x & 8191;
        int p = rec.x >> 13;
        int pos = atomicAdd(&cnt_p[p], 1);
        if (pos < CAP_P) list_p[(size_t)p * CAP_P + pos] = make_int2(h, rec.y);
        else { int o = atomicAdd(ovf_cnt, 1); if (o < OVF_CAP) ovf[o] = rec; }
    }
}

// ---------------- fused gather + attention (R24: f16 feat gather) ----------------
__global__ void k_he(
    const short* __restrict__ feat16,
    const int* __restrict__ cnt_he, const int2* __restrict__ list_he,
    const int2* __restrict__ ovf_he, const int* __restrict__ ovf_he_cnt,
    const float* __restrict__ Wh1, const float* __restrict__ bh1,
    const float* __restrict__ Wh2, const float* __restrict__ bh2,
    const float* __restrict__ Wfuse,
    float* __restrict__ he_weighted) {
    __shared__ float ptl[4][D_IN];     // per-wave partial rows
    __shared__ float hef[D_IN];
    __shared__ float attnv[N_HEADS];
    __shared__ float heattn;
    int h = blockIdx.x;
    int t = threadIdx.x;
    int wv = t >> 6, lane = t & 63;

    int n = cnt_he[h]; if (n > CAP_HE) n = CAP_HE;
    const int2* lst = list_he + (size_t)h * CAP_HE;
    float2 acc = make_float2(0.f, 0.f);
    #pragma unroll 4
    for (int k = wv; k < n; k += 4) {
        int2 pr = lst[k];               // broadcast within wave
        union { unsigned u; _Float16 hh[2]; } cv;
        cv.u = *(const unsigned*)(feat16 + (size_t)(unsigned)pr.x * D_IN + lane * 2);
        float w = __int_as_float(pr.y);
        acc.x += (float)cv.hh[0] * w; acc.y += (float)cv.hh[1] * w;
    }
    int oc = min(*ovf_he_cnt, OVF_CAP); // normally 0; entries are packed recs
    for (int k = wv; k < oc; k += 4) {
        int2 rec = ovf_he[k];
        if ((rec.x & 8191) == h) {
            union { unsigned u; _Float16 hh[2]; } cv;
            cv.u = *(const unsigned*)(feat16 + (size_t)(unsigned)(rec.x >> 13) * D_IN + lane * 2);
            float w = __int_as_float(rec.y);
            acc.x += (float)cv.hh[0] * w; acc.y += (float)cv.hh[1] * w;
        }
    }
    ptl[wv][lane * 2] = acc.x;
    ptl[wv][lane * 2 + 1] = acc.y;
    __syncthreads();
    if (t < D_IN) hef[t] = ptl[0][t] + ptl[1][t] + ptl[2][t] + ptl[3][t];
    __syncthreads();

    int head = wv, k = lane;
    float s = bh1[head * HEAD_DIM + k];
    for (int dd = 0; dd < D_IN; ++dd)
        s += hef[dd] * Wh1[(head * D_IN + dd) * HEAD_DIM + k];
    s = fmaxf(s, 0.f);
    float val = s * Wh2[head * HEAD_DIM + k];
    for (int off = 32; off; off >>= 1) val += __shfl_down(val, off);
    if (k == 0) {
        float x = val + bh2[head];
        attnv[head] = 1.f / (1.f + expf(-x));
    }
    __syncthreads();
    if (t == 0) {
        float ha = 0.f;
        #pragma unroll
        for (int hh = 0; hh < N_HEADS; ++hh) ha += attnv[hh] * Wfuse[hh];
        heattn = ha;
    }
    __syncthreads();
    if (t < D_IN) he_weighted[h * D_IN + t] = hef[t] * heattn;
}

// ---------------- cluster gather (1 protein / 128-thread block) ----------------
__global__ void k_gather_clu(
    const float* __restrict__ he_weighted,
    const int* __restrict__ cnt_p, const int2* __restrict__ list_p,
    const int2* __restrict__ ovf_p, const int* __restrict__ ovf_p_cnt,
    float* __restrict__ cluster_feat) {
    int p = blockIdx.x;
    int n = cnt_p[p]; if (n > CAP_P) n = CAP_P;
    const int2* lst = list_p + (size_t)p * CAP_P;
    int d = threadIdx.x;
    float acc = 0.f;
    #pragma unroll 4
    for (int k = 0; k < n; ++k) {
        int2 pr = lst[k];
        acc += he_weighted[(unsigned)pr.x * D_IN + d] * __int_as_float(pr.y);
    }
    int oc = min(*ovf_p_cnt, OVF_CAP);
    for (int k = 0; k < oc; ++k) {
        int2 rec = ovf_p[k];
        if ((rec.x >> 13) == p)
            acc += he_weighted[(unsigned)(rec.x & 8191) * D_IN + d] * __int_as_float(rec.y);
    }
    cluster_feat[p * D_IN + d] = acc;
}

// ---------------- R25: FUSED MLP (mlp1 + mlp23) — cat lives in LDS, never HBM ----------------
// Stage A: cat = [feat@Wself+b | clu@Wclu+b] (bf16 hi/lo 3-MFMA, proven) -> catS f16 (LDS).
// Stage C/D/softmax/fuse identical to R17's k_mlp23, reading cat from LDS.
// Eliminates 25.6 MB catF write + ~35 MB catF read from HBM and one kernel's latency chain.
__global__ __launch_bounds__(256, 2) void k_mlp(
    const float* __restrict__ feat, const float* __restrict__ cluster_feat,
    const short* __restrict__ WselfT_hi, const short* __restrict__ WselfT_lo, const float* __restrict__ bself,
    const short* __restrict__ WcluT_hi,  const short* __restrict__ WcluT_lo,  const float* __restrict__ bclu,
    const short* __restrict__ Wf1T_h, const float* __restrict__ bf1,
    const short* __restrict__ Wf2T_h, const float* __restrict__ bf2,
    const float* __restrict__ Wf3, const float* __restrict__ bf3,
    float* __restrict__ out) {
    __shared__ __align__(16) short catS[64 * CS2];   // 33.8 KB (f16 cat tile)
    __shared__ __align__(16) short h1S[64 * CS2];    // 33.8 KB (f16 h1)
    __shared__ float fw[64 * 2];
    float* h2F = (float*)h1S;        // alias: h1 dead before h2 written (sync-guarded)
    int t = threadIdx.x;
    int wv = t >> 6, lane = t & 63, col = lane & 15, q = lane >> 4;
    int m0 = blockIdx.x * 64;
    int tiles = NTILE_TOT - blockIdx.x * 4; if (tiles > 4) tiles = 4;
    int rows = tiles * 16;

    // ---- stage A: cat tile -> catS (bf16 hi/lo input split, f16 store) ----
    {
        const float* A = (wv < 2) ? feat : cluster_feat;
        const short* bHi = (wv < 2) ? WselfT_hi : WcluT_hi;
        const short* bLo = (wv < 2) ? WselfT_lo : WcluT_lo;
        const float* bias = (wv < 2) ? bself : bclu;
        int nb = (wv & 1) * 64;
        int cofs = (wv < 2) ? 0 : 128;

        for (int ih = 0; ih < 2; ++ih) {
            short8 Bh[2][4], Bl[2][4];
            float bv[2];
            #pragma unroll
            for (int i2 = 0; i2 < 2; ++i2) {
                int n = nb + (ih * 2 + i2) * 16 + col;
                bv[i2] = bias[n];
                #pragma unroll
                for (int ks = 0; ks < 4; ++ks) {
                    int kb = ks * 32 + q * 8;
                    Bh[i2][ks] = *(const short8*)&bHi[n * 128 + kb];
                    Bl[i2][ks] = *(const short8*)&bLo[n * 128 + kb];
                }
            }
            for (int mt = 0; mt < tiles; ++mt) {
                int row = m0 + mt * 16 + col;
                f32x4 acc[2];
                acc[0] = (f32x4){0.f, 0.f, 0.f, 0.f};
                acc[1] = (f32x4){0.f, 0.f, 0.f, 0.f};
                #pragma unroll
                for (int ks = 0; ks < 4; ++ks) {
                    int kb = ks * 32 + q * 8;
                    const float* ap = A + (size_t)row * D_IN + kb;
                    float4 a0 = *(const float4*)ap, a1 = *(const float4*)(ap + 4);
                    float av[8] = {a0.x, a0.y, a0.z, a0.w, a1.x, a1.y, a1.z, a1.w};
                    short8 ah, al;
                    #pragma unroll
                    for (int j = 0; j < 8; ++j) {
                        short h = f2bs(av[j]); ah[j] = h; al[j] = f2bs(av[j] - bs2f(h));
                    }
                    #pragma unroll
                    for (int i2 = 0; i2 < 2; ++i2) {
                        acc[i2] = __builtin_amdgcn_mfma_f32_16x16x32_bf16(ah, Bh[i2][ks], acc[i2], 0, 0, 0);
                        acc[i2] = __builtin_amdgcn_mfma_f32_16x16x32_bf16(al, Bh[i2][ks], acc[i2], 0, 0, 0);
                        acc[i2] = __builtin_amdgcn_mfma_f32_16x16x32_bf16(ah, Bl[i2][ks], acc[i2], 0, 0, 0);
                    }
                }
                #pragma unroll
                for (int i2 = 0; i2 < 2; ++i2) {
                    int n = nb + (ih * 2 + i2) * 16 + col;
                    #pragma unroll
                    for (int r = 0; r < 4; ++r) {
                        float v = acc[i2][r] + bv[i2];
                        int rl = mt * 16 + q * 4 + r;
                        catS[rl * CS2 + cofs + n] = f2hs(v);
                    }
                }
            }
        }
    }
    __syncthreads();

    // ---- stage C: h1 = relu(cat @ Wf1 + bf1), f16 (cat from LDS) ----
    for (int ih = 0; ih < 2; ++ih) {
        half8 Bh[2][8];
        float bv[2];
        #pragma unroll
        for (int ii = 0; ii < 2; ++ii) {
            int n = wv * 64 + (ih * 2 + ii) * 16 + col;
            bv[ii] = bf1[n];
            #pragma unroll
            for (int ks = 0; ks < 8; ++ks) {
                int kb = ks * 32 + q * 8;
                Bh[ii][ks] = *(const half8*)&Wf1T_h[n * 256 + kb];
            }
        }
        for (int mt = 0; mt < tiles; ++mt) {
            f32x4 acc[2];
            acc[0] = (f32x4){0.f, 0.f, 0.f, 0.f};
            acc[1] = (f32x4){0.f, 0.f, 0.f, 0.f};
            #pragma unroll
            for (int ks = 0; ks < 8; ++ks) {
                int kb = ks * 32 + q * 8;
                half8 ah = *(const half8*)&catS[(mt * 16 + col) * CS2 + kb];
                #pragma unroll
                for (int ii = 0; ii < 2; ++ii)
                    acc[ii] = __builtin_amdgcn_mfma_f32_16x16x32_f16(ah, Bh[ii][ks], acc[ii], 0, 0, 0);
            }
            #pragma unroll
            for (int ii = 0; ii < 2; ++ii) {
                int n = wv * 64 + (ih * 2 + ii) * 16 + col;
                #pragma unroll
                for (int r = 0; r < 4; ++r) {
                    float v = fmaxf(acc[ii][r] + bv[ii], 0.f);
                    int rl = mt * 16 + q * 4 + r;
                    h1S[rl * CS2 + n] = f2hs(v);
                }
            }
        }
    }
    __syncthreads();

    // ---- stage D: h2 = relu(h1 @ Wf2 + bf2); results in regs ----
    f32x4 acc2[2][4];
    #pragma unroll
    for (int ii = 0; ii < 2; ++ii)
        #pragma unroll
        for (int mt = 0; mt < 4; ++mt) acc2[ii][mt] = (f32x4){0.f, 0.f, 0.f, 0.f};
    for (int ii = 0; ii < 2; ++ii) {
        half8 Bh2[8];
        int n = wv * 32 + ii * 16 + col;
        #pragma unroll
        for (int ks = 0; ks < 8; ++ks) {
            int kb = ks * 32 + q * 8;
            Bh2[ks] = *(const half8*)&Wf2T_h[n * 256 + kb];
        }
        for (int mt = 0; mt < tiles; ++mt) {
            #pragma unroll
            for (int ks = 0; ks < 8; ++ks) {
                int kb = ks * 32 + q * 8;
                half8 ah = *(const half8*)&h1S[(mt * 16 + col) * CS2 + kb];
                acc2[ii][mt] = __builtin_amdgcn_mfma_f32_16x16x32_f16(ah, Bh2[ks], acc2[ii][mt], 0, 0, 0);
            }
        }
    }
    __syncthreads();   // all h1 reads complete before h2F overwrites the aliased region

    #pragma unroll
    for (int ii = 0; ii < 2; ++ii) {
        int n = wv * 32 + ii * 16 + col;
        float bvv = bf2[n];
        for (int mt = 0; mt < tiles; ++mt) {
            #pragma unroll
            for (int r = 0; r < 4; ++r)
                h2F[(mt * 16 + q * 4 + r) * 132 + n] = fmaxf(acc2[ii][mt][r] + bvv, 0.f);
        }
    }
    __syncthreads();

    // ---- logits + softmax: 4 threads per protein row ----
    {
        int p = t >> 2, c = t & 3;
        if (p < rows) {
            float s0 = 0.f, s1 = 0.f;
            for (int n = c * 32; n < c * 32 + 32; ++n) {
                float h = h2F[p * 132 + n];
                s0 += h * Wf3[n * 2 + 0];
                s1 += h * Wf3[n * 2 + 1];
            }
            #pragma unroll
            for (int off = 2; off; off >>= 1) {
                s0 += __shfl_down(s0, off, 4);
                s1 += __shfl_down(s1, off, 4);
            }
            if (c == 0) {
                float l0 = s0 + bf3[0], l1 = s1 + bf3[1];
                float m = fmaxf(l0, l1);
                float e0 = expf(l0 - m), e1 = expf(l1 - m);
                float inv = 1.f / (e0 + e1);
                fw[p * 2 + 0] = e0 * inv;
                fw[p * 2 + 1] = e1 * inv;
            }
        }
    }
    __syncthreads();

    // ---- fuse + residual + relu + store (f16 cat from LDS + fp32 feat) ----
    #pragma unroll
    for (int k = 0; k < 4; ++k) {
        int idx = t + k * 256;           // 0..1023 over 64 rows x 16 j-groups
        int rl = idx >> 4;
        int j = (idx & 15) * 8;
        if (rl < rows) {
            size_t ro = (size_t)(m0 + rl);
            half8 sf = *(const half8*)&catS[rl * CS2 + j];
            half8 cf = *(const half8*)&catS[rl * CS2 + 128 + j];
            const float* fp = feat + ro * D_IN + j;
            float4 f0 = *(const float4*)fp, f1 = *(const float4*)(fp + 4);
            float fe[8] = {f0.x, f0.y, f0.z, f0.w, f1.x, f1.y, f1.z, f1.w};
            float w0 = fw[rl * 2 + 0], w1 = fw[rl * 2 + 1];
            float o[8];
            #pragma unroll
            for (int qq = 0; qq < 8; ++qq) {
                float self_f = (float)sf[qq];
                float clu_f  = (float)cf[qq];
                o[qq] = fmaxf(self_f * w0 + clu_f * w1 + fe[qq], 0.f);
            }
            float* ob = out + ro * D_IN + j;
            *(float4*)ob = make_float4(o[0], o[1], o[2], o[3]);
            *(float4*)(ob + 4) = make_float4(o[4], o[5], o[6], o[7]);
        }
    }
}

extern "C" void kernel_launch(void* const* d_in, const int* in_sizes, int n_in,
                              void* d_out, int out_size, void* d_ws, size_t ws_size,
                              hipStream_t stream) {
    (void)in_sizes; (void)n_in; (void)out_size; (void)ws_size;
    const float* feat   = (const float*)d_in[0];
    const float* edge_w = (const float*)d_in[1];
    const float* Wself  = (const float*)d_in[2];
    const float* bself  = (const float*)d_in[3];
    const float* Wclu   = (const float*)d_in[4];
    const float* bclu   = (const float*)d_in[5];
    const float* Wh1    = (const float*)d_in[6];
    const float* bh1    = (const float*)d_in[7];
    const float* Wh2    = (const float*)d_in[8];
    const float* bh2    = (const float*)d_in[9];
    const float* Wfuse  = (const float*)d_in[10];
    const float* Wf1    = (const float*)d_in[11];
    const float* bf1_   = (const float*)d_in[12];
    const float* Wf2    = (const float*)d_in[13];
    const float* bf2_   = (const float*)d_in[14];
    const float* Wf3    = (const float*)d_in[15];
    const float* bf3_   = (const float*)d_in[16];
    const int* edge_pid = (const int*)d_in[17];
    const int* edge_hid = (const int*)d_in[18];
    float* out = (float*)d_out;

    // ---- workspace carve-up ----
    float* he_feat      = (float*)d_ws;                         // 5000*128
    float* cluster_feat = he_feat + (size_t)N_HE * D_IN;        // 50000*128
    int2* list_he = (int2*)(cluster_feat + (size_t)N_P * D_IN); // 5000*CAP_HE
    int2* list_p  = list_he + (size_t)N_HE * CAP_HE;            // 50000*CAP_P
    int2* binHE   = list_p + (size_t)N_P * CAP_P;               // NBIN_HE*BINCAP_HE
    int2* binP    = binHE + (size_t)NBIN_HE * BINCAP_HE;        // NBIN_P*BINCAP_P
    int2* ovf_he  = binP + (size_t)NBIN_P * BINCAP_P;           // OVF_CAP
    int2* ovf_p   = ovf_he + OVF_CAP;                           // OVF_CAP
    int* cnt_he   = (int*)(ovf_p + OVF_CAP);                    // 5000
    int* cnt_p    = cnt_he + N_HE;                              // 50000
    int* ovf_he_cnt = cnt_p + N_P;                              // 1
    int* ovf_p_cnt  = ovf_he_cnt + 1;                           // 1
    int* bincntHE = ovf_p_cnt + 1;                              // NBIN_HE
    int* bincntP  = bincntHE + NBIN_HE;                         // NBIN_P
    short* WselfT_hi = (short*)(bincntP + NBIN_P);              // 128*128 each
    short* WselfT_lo = WselfT_hi + 128 * 128;
    short* WcluT_hi  = WselfT_lo + 128 * 128;
    short* WcluT_lo  = WcluT_hi + 128 * 128;
    short* Wf1T_h    = WcluT_lo + 128 * 128;                    // 256*256 (f16)
    short* Wf2T_h    = Wf1T_h + 256 * 256;                      // 128*256 (f16)
    short* feat16    = Wf2T_h + 128 * 256;                      // 50000*128 (f16)

    k_prep<<<512, 256, 0, stream>>>(Wself, Wclu, Wf1, Wf2,
                                    WselfT_hi, WselfT_lo, WcluT_hi, WcluT_lo,
                                    Wf1T_h, Wf2T_h);
    k_feat16<<<3125, 256, 0, stream>>>(feat, feat16);
    k_zero_int<<<64, 256, 0, stream>>>(cnt_he,
        (unsigned)(N_HE + N_P + 2 + NBIN_HE + NBIN_P));
    k_binA<<<NBATCH, 256, 0, stream>>>(edge_pid, edge_hid, edge_w,
                                       1, HEB_SHIFT, NBIN_HE, BINCAP_HE,
                                       bincntHE, binHE, ovf_he, ovf_he_cnt);
    k_binA<<<NBATCH, 256, 0, stream>>>(edge_pid, edge_hid, edge_w,
                                       0, PB_SHIFT, NBIN_P, BINCAP_P,
                                       bincntP, binP, ovf_p, ovf_p_cnt);
    k_binB_he<<<NBIN_HE, 256, 0, stream>>>(bincntHE, binHE, cnt_he, list_he,
                                           ovf_he, ovf_he_cnt);
    k_binB_p<<<NBIN_P, 256, 0, stream>>>(bincntP, binP, cnt_p, list_p,
                                         ovf_p, ovf_p_cnt);
    k_he<<<N_HE, 256, 0, stream>>>(feat16, cnt_he, list_he, ovf_he, ovf_he_cnt,
                                   Wh1, bh1, Wh2, bh2, Wfuse, he_feat);
    k_gather_clu<<<N_P, 128, 0, stream>>>(he_feat, cnt_p, list_p, ovf_p, ovf_p_cnt,
                                          cluster_feat);
    k_mlp<<<NCHUNK, 256, 0, stream>>>(feat, cluster_feat,
                                      WselfT_hi, WselfT_lo, bself,
                                      WcluT_hi, WcluT_lo, bclu,
                                      Wf1T_h, bf1_,
                                      Wf2T_h, bf2_,
                                      Wf3, bf3_, out);
}

// Round 23
// 391.063 us; speedup vs baseline: 1.1076x; 1.0016x over previous
//
#include <hip/hip_runtime.h>

#define N_P 50000
#define N_HE 5000
#define N_E 800000
#define D_IN 128
#define D_HID 256
#define N_HEADS 4
#define HEAD_DIM 64
#define CAP_HE 320
#define CAP_P  64
#define NTILE_TOT 3125   // 50000 / 16
#define NCHUNK 782       // ceil(3125 / 4) chunks of 64 rows
#define CS2 264          // LDS stride (f16 shorts) for cat/h1

// ---- radix-bucket parameters (R23, verified) ----
#define NBIN_HE 79       // ceil(5000 / 64)
#define HEB_SHIFT 6
#define BINCAP_HE 16384
#define NBIN_P 98        // ceil(50000 / 512)
#define PB_SHIFT 9
#define BINCAP_P 12288
#define BATCH 2048
#define NBATCH 391       // ceil(N_E / BATCH)
#define OVF_CAP 8192

typedef __attribute__((ext_vector_type(8))) short short8;
typedef __attribute__((ext_vector_type(8))) _Float16 half8;
typedef __attribute__((ext_vector_type(4))) float f32x4;

__device__ __forceinline__ short f2bs(float x) {   // fp32 -> bf16 bits (RNE)
    union { float f; unsigned u; } v; v.f = x;
    unsigned r = (v.u + 0x7FFFu + ((v.u >> 16) & 1u)) >> 16;
    return (short)r;
}
__device__ __forceinline__ float bs2f(short s) {
    union { unsigned u; float f; } v; v.u = ((unsigned)(unsigned short)s) << 16;
    return v.f;
}
__device__ __forceinline__ short f2hs(float x) {   // fp32 -> f16 bits (RNE)
    union { _Float16 h; short s; } v; v.h = (_Float16)x; return v.s;
}

__global__ void k_zero_int(int* __restrict__ p, unsigned n) {
    unsigned i = blockIdx.x * blockDim.x + threadIdx.x;
    unsigned stride = gridDim.x * blockDim.x;
    for (; i < n; i += stride) p[i] = 0;
}

// ---------------- feat -> f16 copy for the gather kernel (R24, verified) ----------------
__global__ void k_feat16(const float* __restrict__ feat, short* __restrict__ feat16) {
    unsigned i = (blockIdx.x * 256u + threadIdx.x) * 8u;   // 3125*256*8 = 6.4M exact
    float4 a0 = *(const float4*)(feat + i);
    float4 a1 = *(const float4*)(feat + i + 4);
    short8 o;
    o[0] = f2hs(a0.x); o[1] = f2hs(a0.y); o[2] = f2hs(a0.z); o[3] = f2hs(a0.w);
    o[4] = f2hs(a1.x); o[5] = f2hs(a1.y); o[6] = f2hs(a1.z); o[7] = f2hs(a1.w);
    *(short8*)(feat16 + i) = o;
}

// ---------------- weight prep ----------------
__global__ void k_prep(
    const float* __restrict__ Wself, const float* __restrict__ Wclu,
    const float* __restrict__ Wf1,   const float* __restrict__ Wf2,
    short* __restrict__ WselfT_hi, short* __restrict__ WselfT_lo,
    short* __restrict__ WcluT_hi,  short* __restrict__ WcluT_lo,
    short* __restrict__ Wf1T_h,
    short* __restrict__ Wf2T_h) {
    unsigned i = blockIdx.x * 256u + threadIdx.x;   // 512*256 = 131072 exact
    if (i < 16384u) {
        unsigned j = i >> 7, d = i & 127u;
        float v = Wself[d * 128 + j];
        short h = f2bs(v);
        WselfT_hi[i] = h; WselfT_lo[i] = f2bs(v - bs2f(h));
    } else if (i < 32768u) {
        unsigned ii = i - 16384u, j = ii >> 7, d = ii & 127u;
        float v = Wclu[d * 128 + j];
        short h = f2bs(v);
        WcluT_hi[ii] = h; WcluT_lo[ii] = f2bs(v - bs2f(h));
    } else if (i < 98304u) {
        unsigned ii = i - 32768u, j = ii >> 8, d = ii & 255u;
        Wf1T_h[ii] = f2hs(Wf1[d * 256 + j]);
    } else {
        unsigned ii = i - 98304u, j = ii >> 8, d = ii & 255u;
        Wf2T_h[ii] = f2hs(Wf2[d * 128 + j]);
    }
}

// ---------------- R23 pass A: LDS-staged coarse binning ----------------
__global__ void k_binA(
    const int* __restrict__ edge_pid, const int* __restrict__ edge_hid,
    const float* __restrict__ edge_w,
    int key_is_h, int shift, int nbin, int bincap,
    int* __restrict__ bincnt, int2* __restrict__ bins,
    int2* __restrict__ ovf, int* __restrict__ ovf_cnt) {
    __shared__ int lcnt[128];
    __shared__ int loffs[128];
    __shared__ int gbase[128];
    __shared__ int2 stage[BATCH];     // 16 KB
    __shared__ short tbin[BATCH];     // 4 KB
    int t = threadIdx.x;
    unsigned base = (unsigned)blockIdx.x * BATCH;
    int count = (int)min((unsigned)BATCH, N_E - base);
    if (t < nbin) lcnt[t] = 0;
    __syncthreads();

    int b_[8], pos_[8]; int2 rec_[8]; bool v_[8];
    #pragma unroll
    for (int j = 0; j < 8; ++j) {
        int i = j * 256 + t;
        v_[j] = (i < count);
        if (v_[j]) {
            unsigned e = base + i;
            int h = edge_hid[e], p = edge_pid[e];
            int wbits = __float_as_int(edge_w[e]);
            int b = (key_is_h ? h : p) >> shift;
            b_[j] = b;
            rec_[j] = make_int2(h | (p << 13), wbits);
            pos_[j] = atomicAdd(&lcnt[b], 1);
        }
    }
    __syncthreads();
    if (t == 0) {
        int s = 0;
        for (int b = 0; b < nbin; ++b) { loffs[b] = s; s += lcnt[b]; }
    }
    if (t < nbin) gbase[t] = lcnt[t] ? atomicAdd(&bincnt[t], lcnt[t]) : 0;
    __syncthreads();
    #pragma unroll
    for (int j = 0; j < 8; ++j) {
        if (v_[j]) {
            int idx = loffs[b_[j]] + pos_[j];
            stage[idx] = rec_[j];
            tbin[idx] = (short)b_[j];
        }
    }
    __syncthreads();
    for (int i = t; i < count; i += 256) {
        int b = tbin[i];
        int g = gbase[b] + (i - loffs[b]);
        if (g < bincap) bins[(size_t)b * bincap + g] = stage[i];
        else { int o = atomicAdd(ovf_cnt, 1); if (o < OVF_CAP) ovf[o] = stage[i]; }
    }
}

// ---------------- R23 pass B: per-bin scatter into final buckets ----------------
__global__ void k_binB_he(
    const int* __restrict__ bincnt, const int2* __restrict__ bins,
    int* __restrict__ cnt_he, int2* __restrict__ list_he,
    int2* __restrict__ ovf, int* __restrict__ ovf_cnt) {
    int b = blockIdx.x;
    int n = min(bincnt[b], BINCAP_HE);
    const int2* src = bins + (size_t)b * BINCAP_HE;
    for (int k = threadIdx.x; k < n; k += blockDim.x) {
        int2 rec = src[k];
        int h = rec.x & 8191;
        int p = rec.x >> 13;
        int pos = atomicAdd(&cnt_he[h], 1);
        if (pos < CAP_HE) list_he[(size_t)h * CAP_HE + pos] = make_int2(p, rec.y);
        else { int o = atomicAdd(ovf_cnt, 1); if (o < OVF_CAP) ovf[o] = rec; }
    }
}

__global__ void k_binB_p(
    const int* __restrict__ bincnt, const int2* __restrict__ bins,
    int* __restrict__ cnt_p, int2* __restrict__ list_p,
    int2* __restrict__ ovf, int* __restrict__ ovf_cnt) {
    int b = blockIdx.x;
    int n = min(bincnt[b], BINCAP_P);
    const int2* src = bins + (size_t)b * BINCAP_P;
    for (int k = threadIdx.x; k < n; k += blockDim.x) {
        int2 rec = src[k];
        int h = rec.x & 8191;
        int p = rec.x >> 13;
        int pos = atomicAdd(&cnt_p[p], 1);
        if (pos < CAP_P) list_p[(size_t)p * CAP_P + pos] = make_int2(h, rec.y);
        else { int o = atomicAdd(ovf_cnt, 1); if (o < OVF_CAP) ovf[o] = rec; }
    }
}

// ---------------- fused gather + attention (R24: f16 feat gather) ----------------
__global__ void k_he(
    const short* __restrict__ feat16,
    const int* __restrict__ cnt_he, const int2* __restrict__ list_he,
    const int2* __restrict__ ovf_he, const int* __restrict__ ovf_he_cnt,
    const float* __restrict__ Wh1, const float* __restrict__ bh1,
    const float* __restrict__ Wh2, const float* __restrict__ bh2,
    const float* __restrict__ Wfuse,
    float* __restrict__ he_weighted) {
    __shared__ float ptl[4][D_IN];     // per-wave partial rows
    __shared__ float hef[D_IN];
    __shared__ float attnv[N_HEADS];
    __shared__ float heattn;
    int h = blockIdx.x;
    int t = threadIdx.x;
    int wv = t >> 6, lane = t & 63;

    int n = cnt_he[h]; if (n > CAP_HE) n = CAP_HE;
    const int2* lst = list_he + (size_t)h * CAP_HE;
    float2 acc = make_float2(0.f, 0.f);
    #pragma unroll 4
    for (int k = wv; k < n; k += 4) {
        int2 pr = lst[k];               // broadcast within wave
        union { unsigned u; _Float16 hh[2]; } cv;
        cv.u = *(const unsigned*)(feat16 + (size_t)(unsigned)pr.x * D_IN + lane * 2);
        float w = __int_as_float(pr.y);
        acc.x += (float)cv.hh[0] * w; acc.y += (float)cv.hh[1] * w;
    }
    int oc = min(*ovf_he_cnt, OVF_CAP); // normally 0; entries are packed recs
    for (int k = wv; k < oc; k += 4) {
        int2 rec = ovf_he[k];
        if ((rec.x & 8191) == h) {
            union { unsigned u; _Float16 hh[2]; } cv;
            cv.u = *(const unsigned*)(feat16 + (size_t)(unsigned)(rec.x >> 13) * D_IN + lane * 2);
            float w = __int_as_float(rec.y);
            acc.x += (float)cv.hh[0] * w; acc.y += (float)cv.hh[1] * w;
        }
    }
    ptl[wv][lane * 2] = acc.x;
    ptl[wv][lane * 2 + 1] = acc.y;
    __syncthreads();
    if (t < D_IN) hef[t] = ptl[0][t] + ptl[1][t] + ptl[2][t] + ptl[3][t];
    __syncthreads();

    int head = wv, k = lane;
    float s = bh1[head * HEAD_DIM + k];
    for (int dd = 0; dd < D_IN; ++dd)
        s += hef[dd] * Wh1[(head * D_IN + dd) * HEAD_DIM + k];
    s = fmaxf(s, 0.f);
    float val = s * Wh2[head * HEAD_DIM + k];
    for (int off = 32; off; off >>= 1) val += __shfl_down(val, off);
    if (k == 0) {
        float x = val + bh2[head];
        attnv[head] = 1.f / (1.f + expf(-x));
    }
    __syncthreads();
    if (t == 0) {
        float ha = 0.f;
        #pragma unroll
        for (int hh = 0; hh < N_HEADS; ++hh) ha += attnv[hh] * Wfuse[hh];
        heattn = ha;
    }
    __syncthreads();
    if (t < D_IN) he_weighted[h * D_IN + t] = hef[t] * heattn;
}

// ---------------- cluster gather (1 protein / 128-thread block) ----------------
__global__ void k_gather_clu(
    const float* __restrict__ he_weighted,
    const int* __restrict__ cnt_p, const int2* __restrict__ list_p,
    const int2* __restrict__ ovf_p, const int* __restrict__ ovf_p_cnt,
    float* __restrict__ cluster_feat) {
    int p = blockIdx.x;
    int n = cnt_p[p]; if (n > CAP_P) n = CAP_P;
    const int2* lst = list_p + (size_t)p * CAP_P;
    int d = threadIdx.x;
    float acc = 0.f;
    #pragma unroll 4
    for (int k = 0; k < n; ++k) {
        int2 pr = lst[k];
        acc += he_weighted[(unsigned)pr.x * D_IN + d] * __int_as_float(pr.y);
    }
    int oc = min(*ovf_p_cnt, OVF_CAP);
    for (int k = 0; k < oc; ++k) {
        int2 rec = ovf_p[k];
        if ((rec.x >> 13) == p)
            acc += he_weighted[(unsigned)(rec.x & 8191) * D_IN + d] * __int_as_float(rec.y);
    }
    cluster_feat[p * D_IN + d] = acc;
}

// ---------------- R26: FUSED MLP, 8 waves/block (512 thr) — shorter chain, 4 waves/SIMD ----------------
// Same 64-row tile / 68 KB LDS / per-block weight traffic as R25; the n-dimension is
// split across 8 waves (no ih loop), halving per-wave serial work and doubling
// waves/SIMD at constant fixed cost. Math identical to R25.
__global__ __launch_bounds__(512, 2) void k_mlp(
    const float* __restrict__ feat, const float* __restrict__ cluster_feat,
    const short* __restrict__ WselfT_hi, const short* __restrict__ WselfT_lo, const float* __restrict__ bself,
    const short* __restrict__ WcluT_hi,  const short* __restrict__ WcluT_lo,  const float* __restrict__ bclu,
    const short* __restrict__ Wf1T_h, const float* __restrict__ bf1,
    const short* __restrict__ Wf2T_h, const float* __restrict__ bf2,
    const float* __restrict__ Wf3, const float* __restrict__ bf3,
    float* __restrict__ out) {
    __shared__ __align__(16) short catS[64 * CS2];   // 33.8 KB (f16 cat tile)
    __shared__ __align__(16) short h1S[64 * CS2];    // 33.8 KB (f16 h1)
    __shared__ float fw[64 * 2];
    float* h2F = (float*)h1S;        // alias: h1 dead before h2 written (sync-guarded)
    int t = threadIdx.x;
    int wv = t >> 6, lane = t & 63, col = lane & 15, q = lane >> 4;
    int m0 = blockIdx.x * 64;
    int tiles = NTILE_TOT - blockIdx.x * 4; if (tiles > 4) tiles = 4;
    int rows = tiles * 16;

    // ---- stage A: cat tile -> catS. 8 waves: wv<4 self (feat), wv>=4 clu; 32 cols each ----
    {
        const float* A = (wv < 4) ? feat : cluster_feat;
        const short* bHi = (wv < 4) ? WselfT_hi : WcluT_hi;
        const short* bLo = (wv < 4) ? WselfT_lo : WcluT_lo;
        const float* bias = (wv < 4) ? bself : bclu;
        int nb = (wv & 3) * 32;
        int cofs = (wv < 4) ? 0 : 128;

        short8 Bh[2][4], Bl[2][4];
        float bv[2];
        #pragma unroll
        for (int i2 = 0; i2 < 2; ++i2) {
            int n = nb + i2 * 16 + col;
            bv[i2] = bias[n];
            #pragma unroll
            for (int ks = 0; ks < 4; ++ks) {
                int kb = ks * 32 + q * 8;
                Bh[i2][ks] = *(const short8*)&bHi[n * 128 + kb];
                Bl[i2][ks] = *(const short8*)&bLo[n * 128 + kb];
            }
        }
        for (int mt = 0; mt < tiles; ++mt) {
            int row = m0 + mt * 16 + col;
            f32x4 acc[2];
            acc[0] = (f32x4){0.f, 0.f, 0.f, 0.f};
            acc[1] = (f32x4){0.f, 0.f, 0.f, 0.f};
            #pragma unroll
            for (int ks = 0; ks < 4; ++ks) {
                int kb = ks * 32 + q * 8;
                const float* ap = A + (size_t)row * D_IN + kb;
                float4 a0 = *(const float4*)ap, a1 = *(const float4*)(ap + 4);
                float av[8] = {a0.x, a0.y, a0.z, a0.w, a1.x, a1.y, a1.z, a1.w};
                short8 ah, al;
                #pragma unroll
                for (int j = 0; j < 8; ++j) {
                    short h = f2bs(av[j]); ah[j] = h; al[j] = f2bs(av[j] - bs2f(h));
                }
                #pragma unroll
                for (int i2 = 0; i2 < 2; ++i2) {
                    acc[i2] = __builtin_amdgcn_mfma_f32_16x16x32_bf16(ah, Bh[i2][ks], acc[i2], 0, 0, 0);
                    acc[i2] = __builtin_amdgcn_mfma_f32_16x16x32_bf16(al, Bh[i2][ks], acc[i2], 0, 0, 0);
                    acc[i2] = __builtin_amdgcn_mfma_f32_16x16x32_bf16(ah, Bl[i2][ks], acc[i2], 0, 0, 0);
                }
            }
            #pragma unroll
            for (int i2 = 0; i2 < 2; ++i2) {
                int n = nb + i2 * 16 + col;
                #pragma unroll
                for (int r = 0; r < 4; ++r) {
                    float v = acc[i2][r] + bv[i2];
                    int rl = mt * 16 + q * 4 + r;
                    catS[rl * CS2 + cofs + n] = f2hs(v);
                }
            }
        }
    }
    __syncthreads();

    // ---- stage C: h1 = relu(cat @ Wf1 + bf1), f16; 8 waves x 32 n-cols ----
    {
        half8 Bh[2][8];
        float bv[2];
        #pragma unroll
        for (int i2 = 0; i2 < 2; ++i2) {
            int n = wv * 32 + i2 * 16 + col;
            bv[i2] = bf1[n];
            #pragma unroll
            for (int ks = 0; ks < 8; ++ks) {
                int kb = ks * 32 + q * 8;
                Bh[i2][ks] = *(const half8*)&Wf1T_h[n * 256 + kb];
            }
        }
        for (int mt = 0; mt < tiles; ++mt) {
            f32x4 acc[2];
            acc[0] = (f32x4){0.f, 0.f, 0.f, 0.f};
            acc[1] = (f32x4){0.f, 0.f, 0.f, 0.f};
            #pragma unroll
            for (int ks = 0; ks < 8; ++ks) {
                int kb = ks * 32 + q * 8;
                half8 ah = *(const half8*)&catS[(mt * 16 + col) * CS2 + kb];
                #pragma unroll
                for (int i2 = 0; i2 < 2; ++i2)
                    acc[i2] = __builtin_amdgcn_mfma_f32_16x16x32_f16(ah, Bh[i2][ks], acc[i2], 0, 0, 0);
            }
            #pragma unroll
            for (int i2 = 0; i2 < 2; ++i2) {
                int n = wv * 32 + i2 * 16 + col;
                #pragma unroll
                for (int r = 0; r < 4; ++r) {
                    float v = fmaxf(acc[i2][r] + bv[i2], 0.f);
                    int rl = mt * 16 + q * 4 + r;
                    h1S[rl * CS2 + n] = f2hs(v);
                }
            }
        }
    }
    __syncthreads();

    // ---- stage D: h2 = relu(h1 @ Wf2 + bf2); 8 waves x 16 n-cols; results in regs ----
    {
        half8 Bh2[8];
        int n = wv * 16 + col;
        float bvv = bf2[n];
        #pragma unroll
        for (int ks = 0; ks < 8; ++ks) {
            int kb = ks * 32 + q * 8;
            Bh2[ks] = *(const half8*)&Wf2T_h[n * 256 + kb];
        }
        f32x4 acc2[4];
        #pragma unroll
        for (int mt = 0; mt < 4; ++mt) acc2[mt] = (f32x4){0.f, 0.f, 0.f, 0.f};
        for (int mt = 0; mt < tiles; ++mt) {
            #pragma unroll
            for (int ks = 0; ks < 8; ++ks) {
                int kb = ks * 32 + q * 8;
                half8 ah = *(const half8*)&h1S[(mt * 16 + col) * CS2 + kb];
                acc2[mt] = __builtin_amdgcn_mfma_f32_16x16x32_f16(ah, Bh2[ks], acc2[mt], 0, 0, 0);
            }
        }
        __syncthreads();   // all h1 reads complete before h2F overwrites the aliased region

        for (int mt = 0; mt < tiles; ++mt) {
            #pragma unroll
            for (int r = 0; r < 4; ++r)
                h2F[(mt * 16 + q * 4 + r) * 132 + n] = fmaxf(acc2[mt][r] + bvv, 0.f);
        }
    }
    __syncthreads();

    // ---- logits + softmax: 8 threads per protein row ----
    {
        int p = t >> 3, c = t & 7;
        if (p < rows) {
            float s0 = 0.f, s1 = 0.f;
            for (int n = c * 16; n < c * 16 + 16; ++n) {
                float h = h2F[p * 132 + n];
                s0 += h * Wf3[n * 2 + 0];
                s1 += h * Wf3[n * 2 + 1];
            }
            #pragma unroll
            for (int off = 4; off; off >>= 1) {
                s0 += __shfl_down(s0, off, 8);
                s1 += __shfl_down(s1, off, 8);
            }
            if (c == 0) {
                float l0 = s0 + bf3[0], l1 = s1 + bf3[1];
                float m = fmaxf(l0, l1);
                float e0 = expf(l0 - m), e1 = expf(l1 - m);
                float inv = 1.f / (e0 + e1);
                fw[p * 2 + 0] = e0 * inv;
                fw[p * 2 + 1] = e1 * inv;
            }
        }
    }
    __syncthreads();

    // ---- fuse + residual + relu + store (f16 cat from LDS + fp32 feat) ----
    #pragma unroll
    for (int k = 0; k < 2; ++k) {
        int idx = t + k * 512;           // 0..1023 over 64 rows x 16 j-groups
        int rl = idx >> 4;
        int j = (idx & 15) * 8;
        if (rl < rows) {
            size_t ro = (size_t)(m0 + rl);
            half8 sf = *(const half8*)&catS[rl * CS2 + j];
            half8 cf = *(const half8*)&catS[rl * CS2 + 128 + j];
            const float* fp = feat + ro * D_IN + j;
            float4 f0 = *(const float4*)fp, f1 = *(const float4*)(fp + 4);
            float fe[8] = {f0.x, f0.y, f0.z, f0.w, f1.x, f1.y, f1.z, f1.w};
            float w0 = fw[rl * 2 + 0], w1 = fw[rl * 2 + 1];
            float o[8];
            #pragma unroll
            for (int qq = 0; qq < 8; ++qq) {
                float self_f = (float)sf[qq];
                float clu_f  = (float)cf[qq];
                o[qq] = fmaxf(self_f * w0 + clu_f * w1 + fe[qq], 0.f);
            }
            float* ob = out + ro * D_IN + j;
            *(float4*)ob = make_float4(o[0], o[1], o[2], o[3]);
            *(float4*)(ob + 4) = make_float4(o[4], o[5], o[6], o[7]);
        }
    }
}

extern "C" void kernel_launch(void* const* d_in, const int* in_sizes, int n_in,
                              void* d_out, int out_size, void* d_ws, size_t ws_size,
                              hipStream_t stream) {
    (void)in_sizes; (void)n_in; (void)out_size; (void)ws_size;
    const float* feat   = (const float*)d_in[0];
    const float* edge_w = (const float*)d_in[1];
    const float* Wself  = (const float*)d_in[2];
    const float* bself  = (const float*)d_in[3];
    const float* Wclu   = (const float*)d_in[4];
    const float* bclu   = (const float*)d_in[5];
    const float* Wh1    = (const float*)d_in[6];
    const float* bh1    = (const float*)d_in[7];
    const float* Wh2    = (const float*)d_in[8];
    const float* bh2    = (const float*)d_in[9];
    const float* Wfuse  = (const float*)d_in[10];
    const float* Wf1    = (const float*)d_in[11];
    const float* bf1_   = (const float*)d_in[12];
    const float* Wf2    = (const float*)d_in[13];
    const float* bf2_   = (const float*)d_in[14];
    const float* Wf3    = (const float*)d_in[15];
    const float* bf3_   = (const float*)d_in[16];
    const int* edge_pid = (const int*)d_in[17];
    const int* edge_hid = (const int*)d_in[18];
    float* out = (float*)d_out;

    // ---- workspace carve-up ----
    float* he_feat      = (float*)d_ws;                         // 5000*128
    float* cluster_feat = he_feat + (size_t)N_HE * D_IN;        // 50000*128
    int2* list_he = (int2*)(cluster_feat + (size_t)N_P * D_IN); // 5000*CAP_HE
    int2* list_p  = list_he + (size_t)N_HE * CAP_HE;            // 50000*CAP_P
    int2* binHE   = list_p + (size_t)N_P * CAP_P;               // NBIN_HE*BINCAP_HE
    int2* binP    = binHE + (size_t)NBIN_HE * BINCAP_HE;        // NBIN_P*BINCAP_P
    int2* ovf_he  = binP + (size_t)NBIN_P * BINCAP_P;           // OVF_CAP
    int2* ovf_p   = ovf_he + OVF_CAP;                           // OVF_CAP
    int* cnt_he   = (int*)(ovf_p + OVF_CAP);                    // 5000
    int* cnt_p    = cnt_he + N_HE;                              // 50000
    int* ovf_he_cnt = cnt_p + N_P;                              // 1
    int* ovf_p_cnt  = ovf_he_cnt + 1;                           // 1
    int* bincntHE = ovf_p_cnt + 1;                              // NBIN_HE
    int* bincntP  = bincntHE + NBIN_HE;                         // NBIN_P
    short* WselfT_hi = (short*)(bincntP + NBIN_P);              // 128*128 each
    short* WselfT_lo = WselfT_hi + 128 * 128;
    short* WcluT_hi  = WselfT_lo + 128 * 128;
    short* WcluT_lo  = WcluT_hi + 128 * 128;
    short* Wf1T_h    = WcluT_lo + 128 * 128;                    // 256*256 (f16)
    short* Wf2T_h    = Wf1T_h + 256 * 256;                      // 128*256 (f16)
    short* feat16    = Wf2T_h + 128 * 256;                      // 50000*128 (f16)

    k_prep<<<512, 256, 0, stream>>>(Wself, Wclu, Wf1, Wf2,
                                    WselfT_hi, WselfT_lo, WcluT_hi, WcluT_lo,
                                    Wf1T_h, Wf2T_h);
    k_feat16<<<3125, 256, 0, stream>>>(feat, feat16);
    k_zero_int<<<64, 256, 0, stream>>>(cnt_he,
        (unsigned)(N_HE + N_P + 2 + NBIN_HE + NBIN_P));
    k_binA<<<NBATCH, 256, 0, stream>>>(edge_pid, edge_hid, edge_w,
                                       1, HEB_SHIFT, NBIN_HE, BINCAP_HE,
                                       bincntHE, binHE, ovf_he, ovf_he_cnt);
    k_binA<<<NBATCH, 256, 0, stream>>>(edge_pid, edge_hid, edge_w,
                                       0, PB_SHIFT, NBIN_P, BINCAP_P,
                                       bincntP, binP, ovf_p, ovf_p_cnt);
    k_binB_he<<<NBIN_HE, 256, 0, stream>>>(bincntHE, binHE, cnt_he, list_he,
                                           ovf_he, ovf_he_cnt);
    k_binB_p<<<NBIN_P, 256, 0, stream>>>(bincntP, binP, cnt_p, list_p,
                                         ovf_p, ovf_p_cnt);
    k_he<<<N_HE, 256, 0, stream>>>(feat16, cnt_he, list_he, ovf_he, ovf_he_cnt,
                                   Wh1, bh1, Wh2, bh2, Wfuse, he_feat);
    k_gather_clu<<<N_P, 128, 0, stream>>>(he_feat, cnt_p, list_p, ovf_p, ovf_p_cnt,
                                          cluster_feat);
    k_mlp<<<NCHUNK, 512, 0, stream>>>(feat, cluster_feat,
                                      WselfT_hi, WselfT_lo, bself,
                                      WcluT_hi, WcluT_lo, bclu,
                                      Wf1T_h, bf1_,
                                      Wf2T_h, bf2_,
                                      Wf3, bf3_, out);
}